// Round 9
// baseline (308.605 us; speedup 1.0000x reference)
//
#include <hip/hip_runtime.h>

// ---------------------------------------------------------------------------
// CriticNetwork: 2x GCNConv (relu) + MLP head + per-graph mean.
// Round 9 (= R8 + compile fix): source-blocked two-phase aggregation. Fine
// sort emits per-row src<N/2 split (row_mid); each layer's gather runs as two
// launches whose gather working set (3.2 MB) fits per-XCD L2. fp32 partials
// between phases (non-temporal, ext-vector type for the builtins).
// ---------------------------------------------------------------------------

typedef _Float16 half_t;
typedef __attribute__((ext_vector_type(8))) _Float16 half8;
typedef __attribute__((ext_vector_type(4))) float f32x4;

#define CHUNK 8192    // edges per sort block
#define BKN   128     // nodes per coarse bucket
#define NBMAX 1024    // max coarse buckets (N <= 131072)

__global__ void k_zero_out(float* out, int n) {
    int i = blockIdx.x * blockDim.x + threadIdx.x;
    if (i < n) out[i] = 0.0f;
}

// ---- coarse counting sort ------------------------------------------------

__global__ __launch_bounds__(256) void k_count_coarse(
    const int* __restrict__ dst, int* __restrict__ table, int E, int nblk, int NB)
{
    __shared__ int cnt[NBMAX];
    const int tid = threadIdx.x;
    for (int i = tid; i < NB; i += 256) cnt[i] = 0;
    __syncthreads();
    const int base = blockIdx.x * CHUNK;
    const int lim = min(CHUNK, E - base);
    if (lim == CHUNK) {
        const int4* d4 = (const int4*)(dst + base);
        for (int i = tid; i < CHUNK / 4; i += 256) {
            int4 v = d4[i];
            atomicAdd(&cnt[v.x >> 7], 1);
            atomicAdd(&cnt[v.y >> 7], 1);
            atomicAdd(&cnt[v.z >> 7], 1);
            atomicAdd(&cnt[v.w >> 7], 1);
        }
    } else {
        for (int i = tid; i < lim; i += 256) atomicAdd(&cnt[dst[base + i] >> 7], 1);
    }
    __syncthreads();
    for (int b = tid; b < NB; b += 256) table[b * nblk + blockIdx.x] = cnt[b];
}

__global__ __launch_bounds__(256) void k_scan1(const int* __restrict__ cnts, int* __restrict__ S,
                                               int* __restrict__ bsums, int T) {
    __shared__ int sh[256];
    int t = threadIdx.x;
    int i = blockIdx.x * 256 + t;
    int v = (i < T) ? cnts[i] : 0;
    sh[t] = v;
    __syncthreads();
    for (int off = 1; off < 256; off <<= 1) {
        int tv = (t >= off) ? sh[t - off] : 0;
        __syncthreads();
        sh[t] += tv;
        __syncthreads();
    }
    if (i < T) S[i + 1] = sh[t];
    if (t == 255) bsums[blockIdx.x] = sh[255];
}

__global__ __launch_bounds__(1024) void k_scan2(int* bs, int nb) {
    __shared__ int sh[1024];
    int t = threadIdx.x;
    int v = (t < nb) ? bs[t] : 0;
    sh[t] = v;
    __syncthreads();
    for (int off = 1; off < 1024; off <<= 1) {
        int tv = (t >= off) ? sh[t - off] : 0;
        __syncthreads();
        sh[t] += tv;
        __syncthreads();
    }
    if (t < nb) bs[t] = sh[t] - v;  // exclusive
}

__global__ void k_scan3(int* __restrict__ S, const int* __restrict__ bs, int T) {
    int i = blockIdx.x * blockDim.x + threadIdx.x;
    if (i < T) S[i + 1] += bs[i >> 8];
    if (i == 0) S[0] = 0;
}

__global__ __launch_bounds__(256) void k_scatter2(
    const int* __restrict__ ei, const int* __restrict__ S,
    int* __restrict__ codes, int E, int nblk, int NB)
{
    __shared__ int cur[NBMAX];
    const int tid = threadIdx.x;
    for (int i = tid; i < NB; i += 256) cur[i] = S[i * nblk + blockIdx.x];
    __syncthreads();
    const int base = blockIdx.x * CHUNK;
    const int lim = min(CHUNK, E - base);
    if (lim == CHUNK) {
        const int4* s4 = (const int4*)(ei + base);
        const int4* d4 = (const int4*)(ei + E + base);
        for (int i = tid; i < CHUNK / 4; i += 256) {
            int4 sv = s4[i], dv = d4[i];
            { int pos = atomicAdd(&cur[dv.x >> 7], 1); codes[pos] = ((dv.x & 127) << 17) | sv.x; }
            { int pos = atomicAdd(&cur[dv.y >> 7], 1); codes[pos] = ((dv.y & 127) << 17) | sv.y; }
            { int pos = atomicAdd(&cur[dv.z >> 7], 1); codes[pos] = ((dv.z & 127) << 17) | sv.z; }
            { int pos = atomicAdd(&cur[dv.w >> 7], 1); codes[pos] = ((dv.w & 127) << 17) | sv.w; }
        }
    } else {
        for (int i = tid; i < lim; i += 256) {
            int e = base + i;
            int s = ei[e], d = ei[E + e];
            int pos = atomicAdd(&cur[d >> 7], 1);
            codes[pos] = ((d & 127) << 17) | s;
        }
    }
}

// per-bucket fine CSR with 256 bins: key = (dstLocal<<1) | (src >= Nhalf).
// Emits row_start[n], row_mid[n] (phase split), dinv, dst-sorted esrc.
__global__ __launch_bounds__(256) void k_fine(
    const int* __restrict__ codes, const int* __restrict__ S, int Nhalf,
    int* __restrict__ esrc, int* __restrict__ row_start, int* __restrict__ row_mid,
    float* __restrict__ dinv, int nblk, int N, int E, int NB)
{
    __shared__ int cnt[256];
    __shared__ int sh[256];
    __shared__ int cur[256];
    const int tid = threadIdx.x;
    cnt[tid] = 0;
    __syncthreads();
    const int b = blockIdx.x;
    const int beg = S[b * nblk], end = S[(b + 1) * nblk];
    for (int e = beg + tid; e < end; e += 256) {
        int c = codes[e];
        int key = ((c >> 17) << 1) | ((c & 0x1FFFF) >= Nhalf ? 1 : 0);
        atomicAdd(&cnt[key], 1);
    }
    __syncthreads();
    sh[tid] = cnt[tid];
    __syncthreads();
    for (int off = 1; off < 256; off <<= 1) {
        int tv = (tid >= off) ? sh[tid - off] : 0;
        __syncthreads();
        sh[tid] += tv;
        __syncthreads();
    }
    {
        int fs = beg + sh[tid] - cnt[tid];   // exclusive prefix, global offset
        cur[tid] = fs;
        int n = b * BKN + (tid >> 1);
        if (n < N) {
            if ((tid & 1) == 0) {
                row_start[n] = fs;
                dinv[n] = rsqrtf(1.0f + (float)(cnt[tid] + cnt[tid + 1]));
            } else {
                row_mid[n] = fs;
            }
        }
    }
    if (b == NB - 1 && tid == 0) row_start[N] = E;
    __syncthreads();
    for (int e = beg + tid; e < end; e += 256) {
        int c = codes[e];
        int key = ((c >> 17) << 1) | ((c & 0x1FFFF) >= Nhalf ? 1 : 0);
        int pos = atomicAdd(&cur[key], 1);
        esrc[pos] = c & 0x1FFFF;
    }
}

// ---- dense compute -------------------------------------------------------

// weights -> fp16 transposed; also zeroes out[]
__global__ __launch_bounds__(256) void k_prep(
    const float* __restrict__ W1, const float* __restrict__ W2, const float* __restrict__ Wm1,
    half_t* __restrict__ W1t, half_t* __restrict__ W2t, half_t* __restrict__ Wm1t,
    float* __restrict__ out, int out_n)
{
    int i = blockIdx.x * 256 + threadIdx.x;
    if (i < 128 * 32) { int k = i >> 5, c = i & 31; W1t[c * 128 + k] = (half_t)W1[i]; }
    if (i < 32 * 64)  { int k = i >> 6, c = i & 63; W2t[c * 32 + k]  = (half_t)W2[i]; }
    if (i < 64 * 64)  { int k = i >> 6, c = i & 63; Wm1t[c * 64 + k] = (half_t)Wm1[i]; }
    if (i < out_n) out[i] = 0.0f;
}

// hs1 = fp16( (x @ W1) * dinv ) via MFMA (round 7, unchanged)
__global__ __launch_bounds__(256) void k_gemm1_mfma(
    const float* __restrict__ x, const half_t* __restrict__ W1t,
    const float* __restrict__ dinv, half_t* __restrict__ hs1, int N)
{
    const int tid = threadIdx.x;
    const int wid = tid >> 6, lane = tid & 63;
    const int quad = lane >> 4, n16 = lane & 15;
    const int n0 = blockIdx.x * 64 + wid * 16;
    if (n0 >= N) return;
    const int nrow = min(n0 + n16, N - 1);
    const float* xr = x + (size_t)nrow * 128;
    f32x4 acc0 = {0.f, 0.f, 0.f, 0.f}, acc1 = {0.f, 0.f, 0.f, 0.f};
#pragma unroll
    for (int kc = 0; kc < 4; ++kc) {
        float4 f0 = *(const float4*)(xr + kc * 32 + quad * 8);
        float4 f1 = *(const float4*)(xr + kc * 32 + quad * 8 + 4);
        half8 a;
        a[0] = (half_t)f0.x; a[1] = (half_t)f0.y; a[2] = (half_t)f0.z; a[3] = (half_t)f0.w;
        a[4] = (half_t)f1.x; a[5] = (half_t)f1.y; a[6] = (half_t)f1.z; a[7] = (half_t)f1.w;
        half8 b0 = *(const half8*)(W1t + (size_t)n16 * 128 + kc * 32 + quad * 8);
        half8 b1 = *(const half8*)(W1t + (size_t)(16 + n16) * 128 + kc * 32 + quad * 8);
        acc0 = __builtin_amdgcn_mfma_f32_16x16x32_f16(a, b0, acc0, 0, 0, 0);
        acc1 = __builtin_amdgcn_mfma_f32_16x16x32_f16(a, b1, acc1, 0, 0, 0);
    }
#pragma unroll
    for (int r = 0; r < 4; ++r) {
        int n = n0 + quad * 4 + r;
        if (n < N) {
            float dv = dinv[n];
            hs1[(size_t)n * 32 + n16]      = (half_t)(acc0[r] * dv);
            hs1[(size_t)n * 32 + 16 + n16] = (half_t)(acc1[r] * dv);
        }
    }
}

// phase 0: acc = self + sum of src<Nhalf edges; write fp32 partials (nt).
__global__ __launch_bounds__(256) void k_agg_p0(
    const int* __restrict__ row_start, const int* __restrict__ row_mid,
    const int* __restrict__ esrc, const half_t* __restrict__ IN,
    float* __restrict__ accf, int N)
{
    const int tid = threadIdx.x;
    const int g = tid >> 2, l = tid & 3;       // 64 nodes x 4 lanes
    const int n = blockIdx.x * 64 + g;
    if (n >= N) return;
    const half8* IN8 = (const half8*)IN;
    const int beg = row_start[n], mid = row_mid[n];
    half8 self = IN8[(size_t)n * 4 + l];
    float acc[8];
#pragma unroll
    for (int j = 0; j < 8; ++j) acc[j] = (float)self[j];
    int e = beg;
    for (; e + 3 < mid; e += 4) {
        int s0 = __builtin_nontemporal_load(esrc + e);
        int s1 = __builtin_nontemporal_load(esrc + e + 1);
        int s2 = __builtin_nontemporal_load(esrc + e + 2);
        int s3 = __builtin_nontemporal_load(esrc + e + 3);
        half8 v0 = IN8[(size_t)s0 * 4 + l];
        half8 v1 = IN8[(size_t)s1 * 4 + l];
        half8 v2 = IN8[(size_t)s2 * 4 + l];
        half8 v3 = IN8[(size_t)s3 * 4 + l];
#pragma unroll
        for (int j = 0; j < 8; ++j)
            acc[j] += ((float)v0[j] + (float)v1[j]) + ((float)v2[j] + (float)v3[j]);
    }
    for (; e < mid; ++e) {
        half8 v = IN8[(size_t)__builtin_nontemporal_load(esrc + e) * 4 + l];
#pragma unroll
        for (int j = 0; j < 8; ++j) acc[j] += (float)v[j];
    }
    f32x4 o0 = {acc[0], acc[1], acc[2], acc[3]};
    f32x4 o1 = {acc[4], acc[5], acc[6], acc[7]};
    __builtin_nontemporal_store(o0, (f32x4*)(accf + (size_t)n * 32 + l * 8));
    __builtin_nontemporal_store(o1, (f32x4*)(accf + (size_t)n * 32 + l * 8 + 4));
}

// phase 1: acc = partial + sum of src>=Nhalf edges; finalize.
// L1: OUT = fp16( relu(dinv*acc + bias) * dinv );  L2: OUT = fp16( dinv*acc )
template <bool L1>
__global__ __launch_bounds__(256) void k_agg_p1(
    const int* __restrict__ row_start, const int* __restrict__ row_mid,
    const int* __restrict__ esrc, const half_t* __restrict__ IN,
    const float* __restrict__ accf, const float* __restrict__ bias,
    const float* __restrict__ dinv, half_t* __restrict__ OUT, int N)
{
    const int tid = threadIdx.x;
    const int g = tid >> 2, l = tid & 3;
    const int n = blockIdx.x * 64 + g;
    if (n >= N) return;
    const half8* IN8 = (const half8*)IN;
    const int mid = row_mid[n], end = row_start[n + 1];
    f32x4 a0 = __builtin_nontemporal_load((const f32x4*)(accf + (size_t)n * 32 + l * 8));
    f32x4 a1 = __builtin_nontemporal_load((const f32x4*)(accf + (size_t)n * 32 + l * 8 + 4));
    float acc[8] = {a0[0], a0[1], a0[2], a0[3], a1[0], a1[1], a1[2], a1[3]};
    int e = mid;
    for (; e + 3 < end; e += 4) {
        int s0 = __builtin_nontemporal_load(esrc + e);
        int s1 = __builtin_nontemporal_load(esrc + e + 1);
        int s2 = __builtin_nontemporal_load(esrc + e + 2);
        int s3 = __builtin_nontemporal_load(esrc + e + 3);
        half8 v0 = IN8[(size_t)s0 * 4 + l];
        half8 v1 = IN8[(size_t)s1 * 4 + l];
        half8 v2 = IN8[(size_t)s2 * 4 + l];
        half8 v3 = IN8[(size_t)s3 * 4 + l];
#pragma unroll
        for (int j = 0; j < 8; ++j)
            acc[j] += ((float)v0[j] + (float)v1[j]) + ((float)v2[j] + (float)v3[j]);
    }
    for (; e < end; ++e) {
        half8 v = IN8[(size_t)__builtin_nontemporal_load(esrc + e) * 4 + l];
#pragma unroll
        for (int j = 0; j < 8; ++j) acc[j] += (float)v[j];
    }
    const float dv = dinv[n];
    half8 o;
    if (L1) {
#pragma unroll
        for (int j = 0; j < 8; ++j) {
            float bb = bias[l * 8 + j];
            o[j] = (half_t)(fmaxf(dv * acc[j] + bb, 0.f) * dv);
        }
    } else {
#pragma unroll
        for (int j = 0; j < 8; ++j) o[j] = (half_t)(dv * acc[j]);
    }
    __builtin_nontemporal_store(o, (half8*)(OUT + (size_t)n * 32 + l * 8));
}

// MFMA tail (round 6, unchanged)
__global__ __launch_bounds__(256) void k_tail_mfma(
    const half_t* __restrict__ Y, const half_t* __restrict__ W2t, const float* __restrict__ b2,
    const half_t* __restrict__ Wm1t, const float* __restrict__ bm1,
    const float* __restrict__ Wm2, const float* __restrict__ bm2,
    const int* __restrict__ nn_p, float* __restrict__ out, int N, int n_graphs)
{
    __shared__ float gacc[32];
    __shared__ __align__(16) half_t Hb[4][16][72];
    const int tid = threadIdx.x;
    if (tid < 32) gacc[tid] = 0.f;
    __syncthreads();
    const int wid = tid >> 6, lane = tid & 63;
    const int quad = lane >> 4, n16 = lane & 15;
    const int n0 = blockIdx.x * 64 + wid * 16;
    if (n0 < N) {
        const int nrow = min(n0 + n16, N - 1);
        half8 a1 = *(const half8*)(Y + (size_t)nrow * 32 + quad * 8);
        f32x4 acc1[4];
#pragma unroll
        for (int t = 0; t < 4; ++t) {
            half8 bf = *(const half8*)(W2t + (size_t)(t * 16 + n16) * 32 + quad * 8);
            f32x4 z = {0.f, 0.f, 0.f, 0.f};
            acc1[t] = __builtin_amdgcn_mfma_f32_16x16x32_f16(a1, bf, z, 0, 0, 0);
        }
#pragma unroll
        for (int t = 0; t < 4; ++t) {
            int c = t * 16 + n16;
            float bb = b2[c];
#pragma unroll
            for (int r = 0; r < 4; ++r)
                Hb[wid][quad * 4 + r][c] = (half_t)fmaxf(acc1[t][r] + bb, 0.f);
        }
        half8 a2lo = *(const half8*)&Hb[wid][n16][quad * 8];
        half8 a2hi = *(const half8*)&Hb[wid][n16][32 + quad * 8];
        f32x4 acc2[4];
#pragma unroll
        for (int t = 0; t < 4; ++t) {
            half8 b0 = *(const half8*)(Wm1t + (size_t)(t * 16 + n16) * 64 + quad * 8);
            half8 b1 = *(const half8*)(Wm1t + (size_t)(t * 16 + n16) * 64 + 32 + quad * 8);
            f32x4 a = {0.f, 0.f, 0.f, 0.f};
            a = __builtin_amdgcn_mfma_f32_16x16x32_f16(a2lo, b0, a, 0, 0, 0);
            a = __builtin_amdgcn_mfma_f32_16x16x32_f16(a2hi, b1, a, 0, 0, 0);
            acc2[t] = a;
        }
        float vsum[4] = {0.f, 0.f, 0.f, 0.f};
#pragma unroll
        for (int t = 0; t < 4; ++t) {
            int c = t * 16 + n16;
            float bb = bm1[c], ww = Wm2[c];
#pragma unroll
            for (int r = 0; r < 4; ++r)
                vsum[r] += fmaxf(acc2[t][r] + bb, 0.f) * ww;
        }
#pragma unroll
        for (int m = 1; m < 16; m <<= 1) {
#pragma unroll
            for (int r = 0; r < 4; ++r) vsum[r] += __shfl_xor(vsum[r], m, 64);
        }
        if (n16 == 0) {
            const int nnv = nn_p[0];
            const float bm2v = bm2[0];
#pragma unroll
            for (int r = 0; r < 4; ++r) {
                int n = n0 + quad * 4 + r;
                if (n < N) {
                    int g = n / nnv;
                    if (g < 32) atomicAdd(&gacc[g], vsum[r] + bm2v);
                }
            }
        }
    }
    __syncthreads();
    if (tid < n_graphs && tid < 32) atomicAdd(&out[tid], gacc[tid] / (float)nn_p[0]);
}

// ---- fallback (atomic) path ----------------------------------------------
__global__ void k_zero_int(int* p, int n) {
    int i = blockIdx.x * blockDim.x + threadIdx.x;
    if (i < n) p[i] = 0;
}
__global__ void k_hist(const int* __restrict__ dst, int* __restrict__ deg, int E) {
    int e = blockIdx.x * blockDim.x + threadIdx.x;
    if (e < E) atomicAdd(&deg[dst[e]], 1);
}
__global__ void k_dinv(const int* __restrict__ deg, float* __restrict__ dinv, int n) {
    int i = blockIdx.x * blockDim.x + threadIdx.x;
    if (i < n) dinv[i] = rsqrtf(1.0f + (float)deg[i]);
}
__global__ __launch_bounds__(256) void k_gemm1f(
    const float* __restrict__ x, const float* __restrict__ W,
    const float* __restrict__ dinv, float* __restrict__ hs1, int N)
{
    __shared__ float Wl[128 * 32];
    __shared__ __align__(16) float Xl[8 * 132];
    const int tid = threadIdx.x;
    for (int i = tid; i < 128 * 32; i += 256) Wl[i] = W[i];
    const int node0 = blockIdx.x * 8;
    {
        int r = tid >> 5, c4 = tid & 31;
        int node = node0 + r;
        float4 v = make_float4(0.f, 0.f, 0.f, 0.f);
        if (node < N) v = ((const float4*)(x + (size_t)node * 128))[c4];
        *(float4*)&Xl[r * 132 + c4 * 4] = v;
    }
    __syncthreads();
    const int row = tid >> 5, f = tid & 31;
    float acc = 0.f;
#pragma unroll
    for (int k = 0; k < 128; k += 4) {
        float4 xv = *(const float4*)&Xl[row * 132 + k];
        acc += xv.x * Wl[(k + 0) * 32 + f];
        acc += xv.y * Wl[(k + 1) * 32 + f];
        acc += xv.z * Wl[(k + 2) * 32 + f];
        acc += xv.w * Wl[(k + 3) * 32 + f];
    }
    const int node = node0 + row;
    if (node < N) hs1[(size_t)node * 32 + f] = acc * dinv[node];
}
__global__ __launch_bounds__(256) void k_gemm2(
    const float* __restrict__ agg1, const float* __restrict__ W,
    const float* __restrict__ dinv, float* __restrict__ hs2, int N)
{
    __shared__ float Wl[32 * 64];
    __shared__ __align__(16) float Zl[4 * 36];
    const int tid = threadIdx.x;
    for (int i = tid; i < 32 * 64; i += 256) Wl[i] = W[i];
    const int node0 = blockIdx.x * 4;
    if (tid < 128) {
        int r = tid >> 5, c = tid & 31;
        int node = node0 + r;
        float v = 0.f;
        if (node < N) v = fmaxf(agg1[(size_t)node * 32 + c], 0.f);
        Zl[r * 36 + c] = v;
    }
    __syncthreads();
    const int row = tid >> 6, f = tid & 63;
    float acc = 0.f;
#pragma unroll
    for (int k = 0; k < 32; k += 4) {
        float4 zv = *(const float4*)&Zl[row * 36 + k];
        acc += zv.x * Wl[(k + 0) * 64 + f];
        acc += zv.y * Wl[(k + 1) * 64 + f];
        acc += zv.z * Wl[(k + 2) * 64 + f];
        acc += zv.w * Wl[(k + 3) * 64 + f];
    }
    int node = node0 + row;
    if (node < N) hs2[(size_t)node * 64 + f] = acc * dinv[node];
}
template <int F>
__global__ void k_agg_init(const float* __restrict__ hs, const float* __restrict__ b,
                           const float* __restrict__ dinv, float* __restrict__ agg, int N)
{
    long long t = (long long)blockIdx.x * blockDim.x + threadIdx.x;
    int n = (int)(t / F), f = (int)(t % F);
    if (n < N) agg[(size_t)n * F + f] = hs[(size_t)n * F + f] * dinv[n] + b[f];
}
template <int F>
__global__ void k_edge_atomic(const int* __restrict__ ei, const float* __restrict__ hs,
                              const float* __restrict__ dinv, float* __restrict__ agg, int E)
{
    long long tid = (long long)blockIdx.x * blockDim.x + threadIdx.x;
    int e = (int)(tid / F), f = (int)(tid % F);
    if (e < E) {
        int s = ei[e], d = ei[E + e];
        atomicAdd(&agg[(size_t)d * F + f], hs[(size_t)s * F + f] * dinv[d]);
    }
}
__global__ __launch_bounds__(256) void k_mlp(
    const float* __restrict__ agg2, const float* __restrict__ Wm1,
    const float* __restrict__ bm1, const float* __restrict__ Wm2,
    const float* __restrict__ bm2, float* __restrict__ vout, int N)
{
    __shared__ float Wl[64 * 64];
    __shared__ float W2l[64];
    __shared__ __align__(16) float Zl[4][64];
    const int tid = threadIdx.x;
    for (int i = tid; i < 64 * 64; i += 256) Wl[i] = Wm1[i];
    if (tid < 64) W2l[tid] = Wm2[tid];
    const int wid = tid >> 6, lane = tid & 63;
    const int node = blockIdx.x * 4 + wid;
    float zv = 0.f;
    if (node < N) zv = fmaxf(agg2[(size_t)node * 64 + lane], 0.f);
    Zl[wid][lane] = zv;
    __syncthreads();
    float t = bm1[lane];
#pragma unroll
    for (int k = 0; k < 64; k += 4) {
        float4 z4 = *(const float4*)&Zl[wid][k];
        t += z4.x * Wl[(k + 0) * 64 + lane];
        t += z4.y * Wl[(k + 1) * 64 + lane];
        t += z4.z * Wl[(k + 2) * 64 + lane];
        t += z4.w * Wl[(k + 3) * 64 + lane];
    }
    t = fmaxf(t, 0.f);
    float val = t * W2l[lane];
#pragma unroll
    for (int off = 32; off > 0; off >>= 1) val += __shfl_down(val, off, 64);
    if (lane == 0 && node < N) vout[node] = val + bm2[0];
}
__global__ void k_reduce(const float* __restrict__ v, const int* __restrict__ num_nodes_p,
                         float* out, int N, int n_graphs)
{
    __shared__ float acc[32];
    int tid = threadIdx.x;
    if (tid < n_graphs) acc[tid] = 0.f;
    __syncthreads();
    int i = blockIdx.x * blockDim.x + tid;
    int nn = num_nodes_p[0];
    if (i < N) {
        int g = i / nn;
        if (g < n_graphs) atomicAdd(&acc[g], v[i]);
    }
    __syncthreads();
    if (tid < n_graphs) atomicAdd(&out[tid], acc[tid] / (float)nn);
}
// ---------------------------------------------------------------------------

extern "C" void kernel_launch(void* const* d_in, const int* in_sizes, int n_in,
                              void* d_out, int out_size, void* d_ws, size_t ws_size,
                              hipStream_t stream)
{
    const float* x   = (const float*)d_in[0];
    const float* W1  = (const float*)d_in[1];
    const float* b1  = (const float*)d_in[2];
    const float* W2  = (const float*)d_in[3];
    const float* b2  = (const float*)d_in[4];
    const float* Wm1 = (const float*)d_in[5];
    const float* bm1 = (const float*)d_in[6];
    const float* Wm2 = (const float*)d_in[7];
    const float* bm2 = (const float*)d_in[8];
    const int*   ei  = (const int*)d_in[9];
    const int*   nn  = (const int*)d_in[10];
    const int N = in_sizes[0] / 128;
    const int E = in_sizes[9] / 2;
    float* out = (float*)d_out;

    const int NB = (N + BKN - 1) / BKN;
    const int nblk = (E + CHUNK - 1) / CHUNK;
    const long long T = (long long)NB * nblk;
    const int nb1 = (int)((T + 255) / 256);
    // ints: table T + S(T+1) + bsums 1024 + codes E + esrc E + row_start N+1
    //     + row_mid N + dinv N + accf 32N + fp16 feats 48N + weights 5120
    const size_t need_ints = (size_t)T + (size_t)(T + 1) + 1024
                           + (size_t)E + (size_t)E + (size_t)(N + 1)
                           + (size_t)N + (size_t)N + 32ull * N + 48ull * N + 5120;
    const bool use_new = (N <= 131072) && (T <= 262144) && (nb1 <= 1024)
                       && (out_size <= 32) && ((E & 3) == 0)
                       && (ws_size >= need_ints * sizeof(int));

    if (use_new) {
        int*    table     = (int*)d_ws;                  // T
        int*    S         = table + T;                   // T+1
        int*    bsums     = S + (T + 1);                 // 1024
        int*    codes     = bsums + 1024;                // E
        int*    esrc      = codes + E;                   // E
        int*    row_start = esrc + E;                    // N+1
        int*    row_mid   = row_start + (N + 1);         // N
        float*  dinv      = (float*)(row_mid + N);       // N
        float*  accf      = dinv + N;                    // 32N
        half_t* hs1h      = (half_t*)(accf + 32 * (size_t)N); // 32N halves
        half_t* Zs        = hs1h + 32 * (size_t)N;       // 32N halves
        half_t* Y         = Zs + 32 * (size_t)N;         // 32N halves
        half_t* W1t       = Y + 32 * (size_t)N;          // 4096 halves
        half_t* W2t       = W1t + 4096;                  // 2048 halves
        half_t* Wm1t      = W2t + 2048;                  // 4096 halves
        const int Nhalf = N / 2;
        const int agrid = (N + 63) / 64;

        k_count_coarse<<<nblk, 256, 0, stream>>>(ei + E, table, E, nblk, NB);
        k_scan1<<<nb1, 256, 0, stream>>>(table, S, bsums, (int)T);
        k_scan2<<<1, 1024, 0, stream>>>(bsums, nb1);
        k_scan3<<<nb1, 256, 0, stream>>>(S, bsums, (int)T);
        k_scatter2<<<nblk, 256, 0, stream>>>(ei, S, codes, E, nblk, NB);
        k_fine<<<NB, 256, 0, stream>>>(codes, S, Nhalf, esrc, row_start, row_mid,
                                       dinv, nblk, N, E, NB);
        k_prep<<<16, 256, 0, stream>>>(W1, W2, Wm1, W1t, W2t, Wm1t, out, out_size);
        k_gemm1_mfma<<<agrid, 256, 0, stream>>>(x, W1t, dinv, hs1h, N);
        k_agg_p0<<<agrid, 256, 0, stream>>>(row_start, row_mid, esrc, hs1h, accf, N);
        k_agg_p1<true><<<agrid, 256, 0, stream>>>(row_start, row_mid, esrc, hs1h,
                                                  accf, b1, dinv, Zs, N);
        k_agg_p0<<<agrid, 256, 0, stream>>>(row_start, row_mid, esrc, Zs, accf, N);
        k_agg_p1<false><<<agrid, 256, 0, stream>>>(row_start, row_mid, esrc, Zs,
                                                   accf, b1, dinv, Y, N);
        k_tail_mfma<<<agrid, 256, 0, stream>>>(Y, W2t, b2, Wm1t, bm1, Wm2, bm2,
                                               nn, out, N, out_size);
    } else {
        // fallback: fp32 atomic scatter path
        const size_t Ns = (size_t)N;
        float* dinv = (float*)d_ws;
        float* B    = dinv + N;
        float* hs1  = B;
        float* agg1 = B + 32 * Ns;
        float* hs2  = B + 64 * Ns;
        float* agg2 = B + 128 * Ns;
        float* vtmp = B;
        int*   deg  = (int*)B;

        const int nb = (N + 255) / 256;
        k_zero_out<<<1, 64, 0, stream>>>(out, out_size);
        k_zero_int<<<nb, 256, 0, stream>>>(deg, N);
        k_hist<<<(E + 255) / 256, 256, 0, stream>>>(ei + E, deg, E);
        k_dinv<<<nb, 256, 0, stream>>>(deg, dinv, N);
        k_gemm1f<<<(N + 7) / 8, 256, 0, stream>>>(x, W1, dinv, hs1, N);
        {
            long long t = (long long)N * 32;
            k_agg_init<32><<<(unsigned)((t + 255) / 256), 256, 0, stream>>>(hs1, b1, dinv, agg1, N);
            t = (long long)E * 32;
            k_edge_atomic<32><<<(unsigned)((t + 255) / 256), 256, 0, stream>>>(ei, hs1, dinv, agg1, E);
        }
        k_gemm2<<<(N + 3) / 4, 256, 0, stream>>>(agg1, W2, dinv, hs2, N);
        {
            long long t = (long long)N * 64;
            k_agg_init<64><<<(unsigned)((t + 255) / 256), 256, 0, stream>>>(hs2, b2, dinv, agg2, N);
            t = (long long)E * 64;
            k_edge_atomic<64><<<(unsigned)((t + 255) / 256), 256, 0, stream>>>(ei, hs2, dinv, agg2, E);
        }
        k_mlp<<<(N + 3) / 4, 256, 0, stream>>>(agg2, Wm1, bm1, Wm2, bm2, vtmp, N);
        k_reduce<<<nb, 256, 0, stream>>>(vtmp, nn, out, N, out_size);
    }
}

// Round 10
// 293.618 us; speedup vs baseline: 1.0510x; 1.0510x over previous
//
#include <hip/hip_runtime.h>

// ---------------------------------------------------------------------------
// CriticNetwork: 2x GCNConv (relu) + MLP head + per-graph mean.
// Round 10: revert two-phase agg (R9 regressed) to R7 single-pass k_aggh
// (+ nontemporal esrc/OUT). Coarse buckets 128 -> 512 nodes (NB=196): scatter
// runs lengthen 10 -> 42 edges, write amplification ~5x -> ~1.4x.
// ---------------------------------------------------------------------------

typedef _Float16 half_t;
typedef __attribute__((ext_vector_type(8))) _Float16 half8;
typedef __attribute__((ext_vector_type(4))) float f32x4;

#define CHUNK 8192    // edges per sort block
#define BKN   512     // nodes per coarse bucket
#define NBMAX 256     // max coarse buckets (N <= 131072)

__global__ void k_zero_out(float* out, int n) {
    int i = blockIdx.x * blockDim.x + threadIdx.x;
    if (i < n) out[i] = 0.0f;
}

// ---- coarse counting sort ------------------------------------------------

__global__ __launch_bounds__(256) void k_count_coarse(
    const int* __restrict__ dst, int* __restrict__ table, int E, int nblk, int NB)
{
    __shared__ int cnt[NBMAX];
    const int tid = threadIdx.x;
    for (int i = tid; i < NB; i += 256) cnt[i] = 0;
    __syncthreads();
    const int base = blockIdx.x * CHUNK;
    const int lim = min(CHUNK, E - base);
    if (lim == CHUNK) {
        const int4* d4 = (const int4*)(dst + base);
        for (int i = tid; i < CHUNK / 4; i += 256) {
            int4 v = d4[i];
            atomicAdd(&cnt[v.x >> 9], 1);
            atomicAdd(&cnt[v.y >> 9], 1);
            atomicAdd(&cnt[v.z >> 9], 1);
            atomicAdd(&cnt[v.w >> 9], 1);
        }
    } else {
        for (int i = tid; i < lim; i += 256) atomicAdd(&cnt[dst[base + i] >> 9], 1);
    }
    __syncthreads();
    for (int b = tid; b < NB; b += 256) table[b * nblk + blockIdx.x] = cnt[b];
}

__global__ __launch_bounds__(256) void k_scan1(const int* __restrict__ cnts, int* __restrict__ S,
                                               int* __restrict__ bsums, int T) {
    __shared__ int sh[256];
    int t = threadIdx.x;
    int i = blockIdx.x * 256 + t;
    int v = (i < T) ? cnts[i] : 0;
    sh[t] = v;
    __syncthreads();
    for (int off = 1; off < 256; off <<= 1) {
        int tv = (t >= off) ? sh[t - off] : 0;
        __syncthreads();
        sh[t] += tv;
        __syncthreads();
    }
    if (i < T) S[i + 1] = sh[t];
    if (t == 255) bsums[blockIdx.x] = sh[255];
}

__global__ __launch_bounds__(1024) void k_scan2(int* bs, int nb) {
    __shared__ int sh[1024];
    int t = threadIdx.x;
    int v = (t < nb) ? bs[t] : 0;
    sh[t] = v;
    __syncthreads();
    for (int off = 1; off < 1024; off <<= 1) {
        int tv = (t >= off) ? sh[t - off] : 0;
        __syncthreads();
        sh[t] += tv;
        __syncthreads();
    }
    if (t < nb) bs[t] = sh[t] - v;  // exclusive
}

__global__ void k_scan3(int* __restrict__ S, const int* __restrict__ bs, int T) {
    int i = blockIdx.x * blockDim.x + threadIdx.x;
    if (i < T) S[i + 1] += bs[i >> 8];
    if (i == 0) S[0] = 0;
}

// scatter: per-block cursor bases in LDS; codes = (dstLocal<<17) | src
__global__ __launch_bounds__(256) void k_scatter2(
    const int* __restrict__ ei, const int* __restrict__ S,
    int* __restrict__ codes, int E, int nblk, int NB)
{
    __shared__ int cur[NBMAX];
    const int tid = threadIdx.x;
    for (int i = tid; i < NB; i += 256) cur[i] = S[i * nblk + blockIdx.x];
    __syncthreads();
    const int base = blockIdx.x * CHUNK;
    const int lim = min(CHUNK, E - base);
    if (lim == CHUNK) {
        const int4* s4 = (const int4*)(ei + base);
        const int4* d4 = (const int4*)(ei + E + base);
        for (int i = tid; i < CHUNK / 4; i += 256) {
            int4 sv = s4[i], dv = d4[i];
            { int pos = atomicAdd(&cur[dv.x >> 9], 1); codes[pos] = ((dv.x & 511) << 17) | sv.x; }
            { int pos = atomicAdd(&cur[dv.y >> 9], 1); codes[pos] = ((dv.y & 511) << 17) | sv.y; }
            { int pos = atomicAdd(&cur[dv.z >> 9], 1); codes[pos] = ((dv.z & 511) << 17) | sv.z; }
            { int pos = atomicAdd(&cur[dv.w >> 9], 1); codes[pos] = ((dv.w & 511) << 17) | sv.w; }
        }
    } else {
        for (int i = tid; i < lim; i += 256) {
            int e = base + i;
            int s = ei[e], d = ei[E + e];
            int pos = atomicAdd(&cur[d >> 9], 1);
            codes[pos] = ((d & 511) << 17) | s;
        }
    }
}

// per-bucket fine CSR (512 nodes/bucket, 512 threads): degree count -> LDS
// scan -> dst-sorted esrc + row_start + dinv
__global__ __launch_bounds__(512) void k_fine(
    const int* __restrict__ codes, const int* __restrict__ S,
    int* __restrict__ esrc, int* __restrict__ row_start,
    float* __restrict__ dinv, int nblk, int N, int E, int NB)
{
    __shared__ int cnt[BKN];
    __shared__ int sh[BKN];
    __shared__ int cur[BKN];
    const int tid = threadIdx.x;
    cnt[tid] = 0;
    __syncthreads();
    const int b = blockIdx.x;
    const int beg = S[b * nblk], end = S[(b + 1) * nblk];
    for (int e = beg + tid; e < end; e += 512) atomicAdd(&cnt[codes[e] >> 17], 1);
    __syncthreads();
    sh[tid] = cnt[tid];
    __syncthreads();
    for (int off = 1; off < 512; off <<= 1) {
        int tv = (tid >= off) ? sh[tid - off] : 0;
        __syncthreads();
        sh[tid] += tv;
        __syncthreads();
    }
    {
        int fs = beg + sh[tid] - cnt[tid];   // exclusive prefix, global offset
        cur[tid] = fs;
        int n = b * BKN + tid;
        if (n < N) {
            row_start[n] = fs;
            dinv[n] = rsqrtf(1.0f + (float)cnt[tid]);
        }
    }
    if (b == NB - 1 && tid == 0) row_start[N] = E;
    __syncthreads();
    for (int e = beg + tid; e < end; e += 512) {
        int c = codes[e];
        int pos = atomicAdd(&cur[c >> 17], 1);
        esrc[pos] = c & 0x1FFFF;
    }
}

// ---- dense compute -------------------------------------------------------

// weights -> fp16 transposed; also zeroes out[]
__global__ __launch_bounds__(256) void k_prep(
    const float* __restrict__ W1, const float* __restrict__ W2, const float* __restrict__ Wm1,
    half_t* __restrict__ W1t, half_t* __restrict__ W2t, half_t* __restrict__ Wm1t,
    float* __restrict__ out, int out_n)
{
    int i = blockIdx.x * 256 + threadIdx.x;
    if (i < 128 * 32) { int k = i >> 5, c = i & 31; W1t[c * 128 + k] = (half_t)W1[i]; }
    if (i < 32 * 64)  { int k = i >> 6, c = i & 63; W2t[c * 32 + k]  = (half_t)W2[i]; }
    if (i < 64 * 64)  { int k = i >> 6, c = i & 63; Wm1t[c * 64 + k] = (half_t)Wm1[i]; }
    if (i < out_n) out[i] = 0.0f;
}

// hs1 = fp16( (x @ W1) * dinv ) via MFMA
__global__ __launch_bounds__(256) void k_gemm1_mfma(
    const float* __restrict__ x, const half_t* __restrict__ W1t,
    const float* __restrict__ dinv, half_t* __restrict__ hs1, int N)
{
    const int tid = threadIdx.x;
    const int wid = tid >> 6, lane = tid & 63;
    const int quad = lane >> 4, n16 = lane & 15;
    const int n0 = blockIdx.x * 64 + wid * 16;
    if (n0 >= N) return;
    const int nrow = min(n0 + n16, N - 1);
    const float* xr = x + (size_t)nrow * 128;
    f32x4 acc0 = {0.f, 0.f, 0.f, 0.f}, acc1 = {0.f, 0.f, 0.f, 0.f};
#pragma unroll
    for (int kc = 0; kc < 4; ++kc) {
        float4 f0 = *(const float4*)(xr + kc * 32 + quad * 8);
        float4 f1 = *(const float4*)(xr + kc * 32 + quad * 8 + 4);
        half8 a;
        a[0] = (half_t)f0.x; a[1] = (half_t)f0.y; a[2] = (half_t)f0.z; a[3] = (half_t)f0.w;
        a[4] = (half_t)f1.x; a[5] = (half_t)f1.y; a[6] = (half_t)f1.z; a[7] = (half_t)f1.w;
        half8 b0 = *(const half8*)(W1t + (size_t)n16 * 128 + kc * 32 + quad * 8);
        half8 b1 = *(const half8*)(W1t + (size_t)(16 + n16) * 128 + kc * 32 + quad * 8);
        acc0 = __builtin_amdgcn_mfma_f32_16x16x32_f16(a, b0, acc0, 0, 0, 0);
        acc1 = __builtin_amdgcn_mfma_f32_16x16x32_f16(a, b1, acc1, 0, 0, 0);
    }
#pragma unroll
    for (int r = 0; r < 4; ++r) {
        int n = n0 + quad * 4 + r;
        if (n < N) {
            float dv = dinv[n];
            hs1[(size_t)n * 32 + n16]      = (half_t)(acc0[r] * dv);
            hs1[(size_t)n * 32 + 16 + n16] = (half_t)(acc1[r] * dv);
        }
    }
}

// node-parallel fp16 CSR gather-reduce; streamed esrc/OUT are non-temporal
// so the random-gathered feature rows keep L2.
template <bool L1>
__global__ __launch_bounds__(256) void k_aggh(
    const int* __restrict__ row_start, const int* __restrict__ esrc,
    const half_t* __restrict__ IN, const float* __restrict__ bias,
    const float* __restrict__ dinv, half_t* __restrict__ OUT, int N)
{
    const int tid = threadIdx.x;
    const int g = tid >> 2, l = tid & 3;       // 64 nodes x 4 lanes
    const int n = blockIdx.x * 64 + g;
    if (n >= N) return;
    const half8* IN8 = (const half8*)IN;       // row = 4 x half8
    const int beg = row_start[n], end = row_start[n + 1];
    half8 self = IN8[(size_t)n * 4 + l];
    float acc[8];
#pragma unroll
    for (int j = 0; j < 8; ++j) acc[j] = (float)self[j];
    int e = beg;
    for (; e + 3 < end; e += 4) {
        int s0 = __builtin_nontemporal_load(esrc + e);
        int s1 = __builtin_nontemporal_load(esrc + e + 1);
        int s2 = __builtin_nontemporal_load(esrc + e + 2);
        int s3 = __builtin_nontemporal_load(esrc + e + 3);
        half8 v0 = IN8[(size_t)s0 * 4 + l];
        half8 v1 = IN8[(size_t)s1 * 4 + l];
        half8 v2 = IN8[(size_t)s2 * 4 + l];
        half8 v3 = IN8[(size_t)s3 * 4 + l];
#pragma unroll
        for (int j = 0; j < 8; ++j)
            acc[j] += ((float)v0[j] + (float)v1[j]) + ((float)v2[j] + (float)v3[j]);
    }
    for (; e < end; ++e) {
        half8 v = IN8[(size_t)__builtin_nontemporal_load(esrc + e) * 4 + l];
#pragma unroll
        for (int j = 0; j < 8; ++j) acc[j] += (float)v[j];
    }
    const float dv = dinv[n];
    half8 o;
    if (L1) {
#pragma unroll
        for (int j = 0; j < 8; ++j) {
            float bb = bias[l * 8 + j];
            o[j] = (half_t)(fmaxf(dv * acc[j] + bb, 0.f) * dv);
        }
    } else {
#pragma unroll
        for (int j = 0; j < 8; ++j) o[j] = (half_t)(dv * acc[j]);
    }
    __builtin_nontemporal_store(o, (half8*)(OUT + (size_t)n * 32 + l * 8));
}

// MFMA tail (unchanged)
__global__ __launch_bounds__(256) void k_tail_mfma(
    const half_t* __restrict__ Y, const half_t* __restrict__ W2t, const float* __restrict__ b2,
    const half_t* __restrict__ Wm1t, const float* __restrict__ bm1,
    const float* __restrict__ Wm2, const float* __restrict__ bm2,
    const int* __restrict__ nn_p, float* __restrict__ out, int N, int n_graphs)
{
    __shared__ float gacc[32];
    __shared__ __align__(16) half_t Hb[4][16][72];
    const int tid = threadIdx.x;
    if (tid < 32) gacc[tid] = 0.f;
    __syncthreads();
    const int wid = tid >> 6, lane = tid & 63;
    const int quad = lane >> 4, n16 = lane & 15;
    const int n0 = blockIdx.x * 64 + wid * 16;
    if (n0 < N) {
        const int nrow = min(n0 + n16, N - 1);
        half8 a1 = *(const half8*)(Y + (size_t)nrow * 32 + quad * 8);
        f32x4 acc1[4];
#pragma unroll
        for (int t = 0; t < 4; ++t) {
            half8 bf = *(const half8*)(W2t + (size_t)(t * 16 + n16) * 32 + quad * 8);
            f32x4 z = {0.f, 0.f, 0.f, 0.f};
            acc1[t] = __builtin_amdgcn_mfma_f32_16x16x32_f16(a1, bf, z, 0, 0, 0);
        }
#pragma unroll
        for (int t = 0; t < 4; ++t) {
            int c = t * 16 + n16;
            float bb = b2[c];
#pragma unroll
            for (int r = 0; r < 4; ++r)
                Hb[wid][quad * 4 + r][c] = (half_t)fmaxf(acc1[t][r] + bb, 0.f);
        }
        half8 a2lo = *(const half8*)&Hb[wid][n16][quad * 8];
        half8 a2hi = *(const half8*)&Hb[wid][n16][32 + quad * 8];
        f32x4 acc2[4];
#pragma unroll
        for (int t = 0; t < 4; ++t) {
            half8 b0 = *(const half8*)(Wm1t + (size_t)(t * 16 + n16) * 64 + quad * 8);
            half8 b1 = *(const half8*)(Wm1t + (size_t)(t * 16 + n16) * 64 + 32 + quad * 8);
            f32x4 a = {0.f, 0.f, 0.f, 0.f};
            a = __builtin_amdgcn_mfma_f32_16x16x32_f16(a2lo, b0, a, 0, 0, 0);
            a = __builtin_amdgcn_mfma_f32_16x16x32_f16(a2hi, b1, a, 0, 0, 0);
            acc2[t] = a;
        }
        float vsum[4] = {0.f, 0.f, 0.f, 0.f};
#pragma unroll
        for (int t = 0; t < 4; ++t) {
            int c = t * 16 + n16;
            float bb = bm1[c], ww = Wm2[c];
#pragma unroll
            for (int r = 0; r < 4; ++r)
                vsum[r] += fmaxf(acc2[t][r] + bb, 0.f) * ww;
        }
#pragma unroll
        for (int m = 1; m < 16; m <<= 1) {
#pragma unroll
            for (int r = 0; r < 4; ++r) vsum[r] += __shfl_xor(vsum[r], m, 64);
        }
        if (n16 == 0) {
            const int nnv = nn_p[0];
            const float bm2v = bm2[0];
#pragma unroll
            for (int r = 0; r < 4; ++r) {
                int n = n0 + quad * 4 + r;
                if (n < N) {
                    int g = n / nnv;
                    if (g < 32) atomicAdd(&gacc[g], vsum[r] + bm2v);
                }
            }
        }
    }
    __syncthreads();
    if (tid < n_graphs && tid < 32) atomicAdd(&out[tid], gacc[tid] / (float)nn_p[0]);
}

// ---- fallback (atomic) path ----------------------------------------------
__global__ void k_zero_int(int* p, int n) {
    int i = blockIdx.x * blockDim.x + threadIdx.x;
    if (i < n) p[i] = 0;
}
__global__ void k_hist(const int* __restrict__ dst, int* __restrict__ deg, int E) {
    int e = blockIdx.x * blockDim.x + threadIdx.x;
    if (e < E) atomicAdd(&deg[dst[e]], 1);
}
__global__ void k_dinv(const int* __restrict__ deg, float* __restrict__ dinv, int n) {
    int i = blockIdx.x * blockDim.x + threadIdx.x;
    if (i < n) dinv[i] = rsqrtf(1.0f + (float)deg[i]);
}
__global__ __launch_bounds__(256) void k_gemm1f(
    const float* __restrict__ x, const float* __restrict__ W,
    const float* __restrict__ dinv, float* __restrict__ hs1, int N)
{
    __shared__ float Wl[128 * 32];
    __shared__ __align__(16) float Xl[8 * 132];
    const int tid = threadIdx.x;
    for (int i = tid; i < 128 * 32; i += 256) Wl[i] = W[i];
    const int node0 = blockIdx.x * 8;
    {
        int r = tid >> 5, c4 = tid & 31;
        int node = node0 + r;
        float4 v = make_float4(0.f, 0.f, 0.f, 0.f);
        if (node < N) v = ((const float4*)(x + (size_t)node * 128))[c4];
        *(float4*)&Xl[r * 132 + c4 * 4] = v;
    }
    __syncthreads();
    const int row = tid >> 5, f = tid & 31;
    float acc = 0.f;
#pragma unroll
    for (int k = 0; k < 128; k += 4) {
        float4 xv = *(const float4*)&Xl[row * 132 + k];
        acc += xv.x * Wl[(k + 0) * 32 + f];
        acc += xv.y * Wl[(k + 1) * 32 + f];
        acc += xv.z * Wl[(k + 2) * 32 + f];
        acc += xv.w * Wl[(k + 3) * 32 + f];
    }
    const int node = node0 + row;
    if (node < N) hs1[(size_t)node * 32 + f] = acc * dinv[node];
}
__global__ __launch_bounds__(256) void k_gemm2(
    const float* __restrict__ agg1, const float* __restrict__ W,
    const float* __restrict__ dinv, float* __restrict__ hs2, int N)
{
    __shared__ float Wl[32 * 64];
    __shared__ __align__(16) float Zl[4 * 36];
    const int tid = threadIdx.x;
    for (int i = tid; i < 32 * 64; i += 256) Wl[i] = W[i];
    const int node0 = blockIdx.x * 4;
    if (tid < 128) {
        int r = tid >> 5, c = tid & 31;
        int node = node0 + r;
        float v = 0.f;
        if (node < N) v = fmaxf(agg1[(size_t)node * 32 + c], 0.f);
        Zl[r * 36 + c] = v;
    }
    __syncthreads();
    const int row = tid >> 6, f = tid & 63;
    float acc = 0.f;
#pragma unroll
    for (int k = 0; k < 32; k += 4) {
        float4 zv = *(const float4*)&Zl[row * 36 + k];
        acc += zv.x * Wl[(k + 0) * 64 + f];
        acc += zv.y * Wl[(k + 1) * 64 + f];
        acc += zv.z * Wl[(k + 2) * 64 + f];
        acc += zv.w * Wl[(k + 3) * 64 + f];
    }
    int node = node0 + row;
    if (node < N) hs2[(size_t)node * 64 + f] = acc * dinv[node];
}
template <int F>
__global__ void k_agg_init(const float* __restrict__ hs, const float* __restrict__ b,
                           const float* __restrict__ dinv, float* __restrict__ agg, int N)
{
    long long t = (long long)blockIdx.x * blockDim.x + threadIdx.x;
    int n = (int)(t / F), f = (int)(t % F);
    if (n < N) agg[(size_t)n * F + f] = hs[(size_t)n * F + f] * dinv[n] + b[f];
}
template <int F>
__global__ void k_edge_atomic(const int* __restrict__ ei, const float* __restrict__ hs,
                              const float* __restrict__ dinv, float* __restrict__ agg, int E)
{
    long long tid = (long long)blockIdx.x * blockDim.x + threadIdx.x;
    int e = (int)(tid / F), f = (int)(tid % F);
    if (e < E) {
        int s = ei[e], d = ei[E + e];
        atomicAdd(&agg[(size_t)d * F + f], hs[(size_t)s * F + f] * dinv[d]);
    }
}
__global__ __launch_bounds__(256) void k_mlp(
    const float* __restrict__ agg2, const float* __restrict__ Wm1,
    const float* __restrict__ bm1, const float* __restrict__ Wm2,
    const float* __restrict__ bm2, float* __restrict__ vout, int N)
{
    __shared__ float Wl[64 * 64];
    __shared__ float W2l[64];
    __shared__ __align__(16) float Zl[4][64];
    const int tid = threadIdx.x;
    for (int i = tid; i < 64 * 64; i += 256) Wl[i] = Wm1[i];
    if (tid < 64) W2l[tid] = Wm2[tid];
    const int wid = tid >> 6, lane = tid & 63;
    const int node = blockIdx.x * 4 + wid;
    float zv = 0.f;
    if (node < N) zv = fmaxf(agg2[(size_t)node * 64 + lane], 0.f);
    Zl[wid][lane] = zv;
    __syncthreads();
    float t = bm1[lane];
#pragma unroll
    for (int k = 0; k < 64; k += 4) {
        float4 z4 = *(const float4*)&Zl[wid][k];
        t += z4.x * Wl[(k + 0) * 64 + lane];
        t += z4.y * Wl[(k + 1) * 64 + lane];
        t += z4.z * Wl[(k + 2) * 64 + lane];
        t += z4.w * Wl[(k + 3) * 64 + lane];
    }
    t = fmaxf(t, 0.f);
    float val = t * W2l[lane];
#pragma unroll
    for (int off = 32; off > 0; off >>= 1) val += __shfl_down(val, off, 64);
    if (lane == 0 && node < N) vout[node] = val + bm2[0];
}
__global__ void k_reduce(const float* __restrict__ v, const int* __restrict__ num_nodes_p,
                         float* out, int N, int n_graphs)
{
    __shared__ float acc[32];
    int tid = threadIdx.x;
    if (tid < n_graphs) acc[tid] = 0.f;
    __syncthreads();
    int i = blockIdx.x * blockDim.x + tid;
    int nn = num_nodes_p[0];
    if (i < N) {
        int g = i / nn;
        if (g < n_graphs) atomicAdd(&acc[g], v[i]);
    }
    __syncthreads();
    if (tid < n_graphs) atomicAdd(&out[tid], acc[tid] / (float)nn);
}
// ---------------------------------------------------------------------------

extern "C" void kernel_launch(void* const* d_in, const int* in_sizes, int n_in,
                              void* d_out, int out_size, void* d_ws, size_t ws_size,
                              hipStream_t stream)
{
    const float* x   = (const float*)d_in[0];
    const float* W1  = (const float*)d_in[1];
    const float* b1  = (const float*)d_in[2];
    const float* W2  = (const float*)d_in[3];
    const float* b2  = (const float*)d_in[4];
    const float* Wm1 = (const float*)d_in[5];
    const float* bm1 = (const float*)d_in[6];
    const float* Wm2 = (const float*)d_in[7];
    const float* bm2 = (const float*)d_in[8];
    const int*   ei  = (const int*)d_in[9];
    const int*   nn  = (const int*)d_in[10];
    const int N = in_sizes[0] / 128;
    const int E = in_sizes[9] / 2;
    float* out = (float*)d_out;

    const int NB = (N + BKN - 1) / BKN;
    const int nblk = (E + CHUNK - 1) / CHUNK;
    const long long T = (long long)NB * nblk;
    const int nb1 = (int)((T + 255) / 256);
    // ints: table T + S(T+1) + bsums 1024 + codes E + esrc E + row_start N+1
    //     + dinv N + fp16 feats 48N + weights 5120
    const size_t need_ints = (size_t)T + (size_t)(T + 1) + 1024
                           + (size_t)E + (size_t)E + (size_t)(N + 1)
                           + (size_t)N + 48ull * N + 5120;
    const bool use_new = (N <= 131072) && (T <= 262144) && (nb1 <= 1024)
                       && (NB <= NBMAX) && (out_size <= 32)
                       && (ws_size >= need_ints * sizeof(int));

    if (use_new) {
        int*    table     = (int*)d_ws;                  // T
        int*    S         = table + T;                   // T+1
        int*    bsums     = S + (T + 1);                 // 1024
        int*    codes     = bsums + 1024;                // E
        int*    esrc      = codes + E;                   // E
        int*    row_start = esrc + E;                    // N+1
        float*  dinv      = (float*)(row_start + N + 1); // N
        half_t* hs1h      = (half_t*)(dinv + N);         // 32N halves
        half_t* Zs        = hs1h + 32 * (size_t)N;       // 32N halves
        half_t* Y         = Zs + 32 * (size_t)N;         // 32N halves
        half_t* W1t       = Y + 32 * (size_t)N;          // 4096 halves
        half_t* W2t       = W1t + 4096;                  // 2048 halves
        half_t* Wm1t      = W2t + 2048;                  // 4096 halves
        const int agrid = (N + 63) / 64;

        k_count_coarse<<<nblk, 256, 0, stream>>>(ei + E, table, E, nblk, NB);
        k_scan1<<<nb1, 256, 0, stream>>>(table, S, bsums, (int)T);
        k_scan2<<<1, 1024, 0, stream>>>(bsums, nb1);
        k_scan3<<<nb1, 256, 0, stream>>>(S, bsums, (int)T);
        k_scatter2<<<nblk, 256, 0, stream>>>(ei, S, codes, E, nblk, NB);
        k_fine<<<NB, 512, 0, stream>>>(codes, S, esrc, row_start, dinv, nblk, N, E, NB);
        k_prep<<<16, 256, 0, stream>>>(W1, W2, Wm1, W1t, W2t, Wm1t, out, out_size);
        k_gemm1_mfma<<<agrid, 256, 0, stream>>>(x, W1t, dinv, hs1h, N);
        k_aggh<true><<<agrid, 256, 0, stream>>>(row_start, esrc, hs1h, b1, dinv, Zs, N);
        k_aggh<false><<<agrid, 256, 0, stream>>>(row_start, esrc, Zs, b1, dinv, Y, N);
        k_tail_mfma<<<agrid, 256, 0, stream>>>(Y, W2t, b2, Wm1t, bm1, Wm2, bm2,
                                               nn, out, N, out_size);
    } else {
        // fallback: fp32 atomic scatter path
        const size_t Ns = (size_t)N;
        float* dinv = (float*)d_ws;
        float* B    = dinv + N;
        float* hs1  = B;
        float* agg1 = B + 32 * Ns;
        float* hs2  = B + 64 * Ns;
        float* agg2 = B + 128 * Ns;
        float* vtmp = B;
        int*   deg  = (int*)B;

        const int nb = (N + 255) / 256;
        k_zero_out<<<1, 64, 0, stream>>>(out, out_size);
        k_zero_int<<<nb, 256, 0, stream>>>(deg, N);
        k_hist<<<(E + 255) / 256, 256, 0, stream>>>(ei + E, deg, E);
        k_dinv<<<nb, 256, 0, stream>>>(deg, dinv, N);
        k_gemm1f<<<(N + 7) / 8, 256, 0, stream>>>(x, W1, dinv, hs1, N);
        {
            long long t = (long long)N * 32;
            k_agg_init<32><<<(unsigned)((t + 255) / 256), 256, 0, stream>>>(hs1, b1, dinv, agg1, N);
            t = (long long)E * 32;
            k_edge_atomic<32><<<(unsigned)((t + 255) / 256), 256, 0, stream>>>(ei, hs1, dinv, agg1, E);
        }
        k_gemm2<<<(N + 3) / 4, 256, 0, stream>>>(agg1, W2, dinv, hs2, N);
        {
            long long t = (long long)N * 64;
            k_agg_init<64><<<(unsigned)((t + 255) / 256), 256, 0, stream>>>(hs2, b2, dinv, agg2, N);
            t = (long long)E * 64;
            k_edge_atomic<64><<<(unsigned)((t + 255) / 256), 256, 0, stream>>>(ei, hs2, dinv, agg2, E);
        }
        k_mlp<<<(N + 3) / 4, 256, 0, stream>>>(agg2, Wm1, bm1, Wm2, bm2, vtmp, N);
        k_reduce<<<nb, 256, 0, stream>>>(vtmp, nn, out, N, out_size);
    }
}

// Round 11
// 262.448 us; speedup vs baseline: 1.1759x; 1.1188x over previous
//
#include <hip/hip_runtime.h>

// ---------------------------------------------------------------------------
// CriticNetwork: 2x GCNConv (relu) + MLP head + per-graph mean.
// Round 11 (= R10 + fp8 gather tables): hs1/Zs stored as OCP fp8 e4m3
// (32 B/row -> 3.2 MB table fits per-XCD L2; half the gather bytes).
// fp32 accumulate; Y stays fp16 for the MFMA tail. Sort path = R10 (BKN=512).
// ---------------------------------------------------------------------------

typedef _Float16 half_t;
typedef __attribute__((ext_vector_type(8))) _Float16 half8;
typedef __attribute__((ext_vector_type(4))) float f32x4;
typedef __attribute__((ext_vector_type(2))) float f32x2;
typedef __attribute__((ext_vector_type(2))) int   i32x2;

#define CHUNK 8192    // edges per sort block
#define BKN   512     // nodes per coarse bucket
#define NBMAX 256     // max coarse buckets (N <= 131072)

__global__ void k_zero_out(float* out, int n) {
    int i = blockIdx.x * blockDim.x + threadIdx.x;
    if (i < n) out[i] = 0.0f;
}

// ---- coarse counting sort ------------------------------------------------

__global__ __launch_bounds__(256) void k_count_coarse(
    const int* __restrict__ dst, int* __restrict__ table, int E, int nblk, int NB)
{
    __shared__ int cnt[NBMAX];
    const int tid = threadIdx.x;
    for (int i = tid; i < NB; i += 256) cnt[i] = 0;
    __syncthreads();
    const int base = blockIdx.x * CHUNK;
    const int lim = min(CHUNK, E - base);
    if (lim == CHUNK) {
        const int4* d4 = (const int4*)(dst + base);
        for (int i = tid; i < CHUNK / 4; i += 256) {
            int4 v = d4[i];
            atomicAdd(&cnt[v.x >> 9], 1);
            atomicAdd(&cnt[v.y >> 9], 1);
            atomicAdd(&cnt[v.z >> 9], 1);
            atomicAdd(&cnt[v.w >> 9], 1);
        }
    } else {
        for (int i = tid; i < lim; i += 256) atomicAdd(&cnt[dst[base + i] >> 9], 1);
    }
    __syncthreads();
    for (int b = tid; b < NB; b += 256) table[b * nblk + blockIdx.x] = cnt[b];
}

__global__ __launch_bounds__(256) void k_scan1(const int* __restrict__ cnts, int* __restrict__ S,
                                               int* __restrict__ bsums, int T) {
    __shared__ int sh[256];
    int t = threadIdx.x;
    int i = blockIdx.x * 256 + t;
    int v = (i < T) ? cnts[i] : 0;
    sh[t] = v;
    __syncthreads();
    for (int off = 1; off < 256; off <<= 1) {
        int tv = (t >= off) ? sh[t - off] : 0;
        __syncthreads();
        sh[t] += tv;
        __syncthreads();
    }
    if (i < T) S[i + 1] = sh[t];
    if (t == 255) bsums[blockIdx.x] = sh[255];
}

__global__ __launch_bounds__(1024) void k_scan2(int* bs, int nb) {
    __shared__ int sh[1024];
    int t = threadIdx.x;
    int v = (t < nb) ? bs[t] : 0;
    sh[t] = v;
    __syncthreads();
    for (int off = 1; off < 1024; off <<= 1) {
        int tv = (t >= off) ? sh[t - off] : 0;
        __syncthreads();
        sh[t] += tv;
        __syncthreads();
    }
    if (t < nb) bs[t] = sh[t] - v;  // exclusive
}

__global__ void k_scan3(int* __restrict__ S, const int* __restrict__ bs, int T) {
    int i = blockIdx.x * blockDim.x + threadIdx.x;
    if (i < T) S[i + 1] += bs[i >> 8];
    if (i == 0) S[0] = 0;
}

__global__ __launch_bounds__(256) void k_scatter2(
    const int* __restrict__ ei, const int* __restrict__ S,
    int* __restrict__ codes, int E, int nblk, int NB)
{
    __shared__ int cur[NBMAX];
    const int tid = threadIdx.x;
    for (int i = tid; i < NB; i += 256) cur[i] = S[i * nblk + blockIdx.x];
    __syncthreads();
    const int base = blockIdx.x * CHUNK;
    const int lim = min(CHUNK, E - base);
    if (lim == CHUNK) {
        const int4* s4 = (const int4*)(ei + base);
        const int4* d4 = (const int4*)(ei + E + base);
        for (int i = tid; i < CHUNK / 4; i += 256) {
            int4 sv = s4[i], dv = d4[i];
            { int pos = atomicAdd(&cur[dv.x >> 9], 1); codes[pos] = ((dv.x & 511) << 17) | sv.x; }
            { int pos = atomicAdd(&cur[dv.y >> 9], 1); codes[pos] = ((dv.y & 511) << 17) | sv.y; }
            { int pos = atomicAdd(&cur[dv.z >> 9], 1); codes[pos] = ((dv.z & 511) << 17) | sv.z; }
            { int pos = atomicAdd(&cur[dv.w >> 9], 1); codes[pos] = ((dv.w & 511) << 17) | sv.w; }
        }
    } else {
        for (int i = tid; i < lim; i += 256) {
            int e = base + i;
            int s = ei[e], d = ei[E + e];
            int pos = atomicAdd(&cur[d >> 9], 1);
            codes[pos] = ((d & 511) << 17) | s;
        }
    }
}

__global__ __launch_bounds__(512) void k_fine(
    const int* __restrict__ codes, const int* __restrict__ S,
    int* __restrict__ esrc, int* __restrict__ row_start,
    float* __restrict__ dinv, int nblk, int N, int E, int NB)
{
    __shared__ int cnt[BKN];
    __shared__ int sh[BKN];
    __shared__ int cur[BKN];
    const int tid = threadIdx.x;
    cnt[tid] = 0;
    __syncthreads();
    const int b = blockIdx.x;
    const int beg = S[b * nblk], end = S[(b + 1) * nblk];
    for (int e = beg + tid; e < end; e += 512) atomicAdd(&cnt[codes[e] >> 17], 1);
    __syncthreads();
    sh[tid] = cnt[tid];
    __syncthreads();
    for (int off = 1; off < 512; off <<= 1) {
        int tv = (tid >= off) ? sh[tid - off] : 0;
        __syncthreads();
        sh[tid] += tv;
        __syncthreads();
    }
    {
        int fs = beg + sh[tid] - cnt[tid];
        cur[tid] = fs;
        int n = b * BKN + tid;
        if (n < N) {
            row_start[n] = fs;
            dinv[n] = rsqrtf(1.0f + (float)cnt[tid]);
        }
    }
    if (b == NB - 1 && tid == 0) row_start[N] = E;
    __syncthreads();
    for (int e = beg + tid; e < end; e += 512) {
        int c = codes[e];
        int pos = atomicAdd(&cur[c >> 17], 1);
        esrc[pos] = c & 0x1FFFF;
    }
}

// ---- dense compute -------------------------------------------------------

// weights -> fp16 transposed; also zeroes out[]
__global__ __launch_bounds__(256) void k_prep(
    const float* __restrict__ W1, const float* __restrict__ W2, const float* __restrict__ Wm1,
    half_t* __restrict__ W1t, half_t* __restrict__ W2t, half_t* __restrict__ Wm1t,
    float* __restrict__ out, int out_n)
{
    int i = blockIdx.x * 256 + threadIdx.x;
    if (i < 128 * 32) { int k = i >> 5, c = i & 31; W1t[c * 128 + k] = (half_t)W1[i]; }
    if (i < 32 * 64)  { int k = i >> 6, c = i & 63; W2t[c * 32 + k]  = (half_t)W2[i]; }
    if (i < 64 * 64)  { int k = i >> 6, c = i & 63; Wm1t[c * 64 + k] = (half_t)Wm1[i]; }
    if (i < out_n) out[i] = 0.0f;
}

// hs1 = fp8( (x @ W1) * dinv ) via MFMA; byte stores (coalesce across n16)
__global__ __launch_bounds__(256) void k_gemm1_mfma(
    const float* __restrict__ x, const half_t* __restrict__ W1t,
    const float* __restrict__ dinv, unsigned char* __restrict__ hs8, int N)
{
    const int tid = threadIdx.x;
    const int wid = tid >> 6, lane = tid & 63;
    const int quad = lane >> 4, n16 = lane & 15;
    const int n0 = blockIdx.x * 64 + wid * 16;
    if (n0 >= N) return;
    const int nrow = min(n0 + n16, N - 1);
    const float* xr = x + (size_t)nrow * 128;
    f32x4 acc0 = {0.f, 0.f, 0.f, 0.f}, acc1 = {0.f, 0.f, 0.f, 0.f};
#pragma unroll
    for (int kc = 0; kc < 4; ++kc) {
        float4 f0 = *(const float4*)(xr + kc * 32 + quad * 8);
        float4 f1 = *(const float4*)(xr + kc * 32 + quad * 8 + 4);
        half8 a;
        a[0] = (half_t)f0.x; a[1] = (half_t)f0.y; a[2] = (half_t)f0.z; a[3] = (half_t)f0.w;
        a[4] = (half_t)f1.x; a[5] = (half_t)f1.y; a[6] = (half_t)f1.z; a[7] = (half_t)f1.w;
        half8 b0 = *(const half8*)(W1t + (size_t)n16 * 128 + kc * 32 + quad * 8);
        half8 b1 = *(const half8*)(W1t + (size_t)(16 + n16) * 128 + kc * 32 + quad * 8);
        acc0 = __builtin_amdgcn_mfma_f32_16x16x32_f16(a, b0, acc0, 0, 0, 0);
        acc1 = __builtin_amdgcn_mfma_f32_16x16x32_f16(a, b1, acc1, 0, 0, 0);
    }
#pragma unroll
    for (int r = 0; r < 4; ++r) {
        int n = n0 + quad * 4 + r;
        if (n < N) {
            float dv = dinv[n];
            int w0 = __builtin_amdgcn_cvt_pk_fp8_f32(acc0[r] * dv, 0.f, 0, false);
            int w1 = __builtin_amdgcn_cvt_pk_fp8_f32(acc1[r] * dv, 0.f, 0, false);
            hs8[(size_t)n * 32 + n16]      = (unsigned char)(w0 & 0xFF);
            hs8[(size_t)n * 32 + 16 + n16] = (unsigned char)(w1 & 0xFF);
        }
    }
}

__device__ __forceinline__ void unpack_acc8(i32x2 w, float* acc) {
    f32x2 p;
    p = __builtin_amdgcn_cvt_pk_f32_fp8(w.x, false); acc[0] += p.x; acc[1] += p.y;
    p = __builtin_amdgcn_cvt_pk_f32_fp8(w.x, true);  acc[2] += p.x; acc[3] += p.y;
    p = __builtin_amdgcn_cvt_pk_f32_fp8(w.y, false); acc[4] += p.x; acc[5] += p.y;
    p = __builtin_amdgcn_cvt_pk_f32_fp8(w.y, true);  acc[6] += p.x; acc[7] += p.y;
}

// node-parallel fp8 CSR gather-reduce; fp32 accumulate. 4 lanes/node, 8 B/lane.
// L1: OUT(fp8) = relu(dinv*acc + bias) * dinv ;  L2: OUT(fp16) = dinv*acc
template <bool L1>
__global__ __launch_bounds__(256) void k_agg8(
    const int* __restrict__ row_start, const int* __restrict__ esrc,
    const int* __restrict__ IN, const float* __restrict__ bias,
    const float* __restrict__ dinv, void* __restrict__ OUT, int N)
{
    const int tid = threadIdx.x;
    const int g = tid >> 2, l = tid & 3;       // 64 nodes x 4 lanes
    const int n = blockIdx.x * 64 + g;
    if (n >= N) return;
    const int beg = row_start[n], end = row_start[n + 1];
    float acc[8] = {0.f, 0.f, 0.f, 0.f, 0.f, 0.f, 0.f, 0.f};
    {
        i32x2 ws_ = *(const i32x2*)(IN + (size_t)n * 8 + l * 2);  // self
        unpack_acc8(ws_, acc);
    }
    int e = beg;
    for (; e + 3 < end; e += 4) {
        int s0 = __builtin_nontemporal_load(esrc + e);
        int s1 = __builtin_nontemporal_load(esrc + e + 1);
        int s2 = __builtin_nontemporal_load(esrc + e + 2);
        int s3 = __builtin_nontemporal_load(esrc + e + 3);
        i32x2 w0 = *(const i32x2*)(IN + (size_t)s0 * 8 + l * 2);
        i32x2 w1 = *(const i32x2*)(IN + (size_t)s1 * 8 + l * 2);
        i32x2 w2 = *(const i32x2*)(IN + (size_t)s2 * 8 + l * 2);
        i32x2 w3 = *(const i32x2*)(IN + (size_t)s3 * 8 + l * 2);
        unpack_acc8(w0, acc);
        unpack_acc8(w1, acc);
        unpack_acc8(w2, acc);
        unpack_acc8(w3, acc);
    }
    for (; e < end; ++e) {
        int s = __builtin_nontemporal_load(esrc + e);
        i32x2 w = *(const i32x2*)(IN + (size_t)s * 8 + l * 2);
        unpack_acc8(w, acc);
    }
    const float dv = dinv[n];
    if (L1) {
        float v[8];
#pragma unroll
        for (int j = 0; j < 8; ++j)
            v[j] = fmaxf(dv * acc[j] + bias[l * 8 + j], 0.f) * dv;
        int o0 = __builtin_amdgcn_cvt_pk_fp8_f32(v[0], v[1], 0, false);
        o0     = __builtin_amdgcn_cvt_pk_fp8_f32(v[2], v[3], o0, true);
        int o1 = __builtin_amdgcn_cvt_pk_fp8_f32(v[4], v[5], 0, false);
        o1     = __builtin_amdgcn_cvt_pk_fp8_f32(v[6], v[7], o1, true);
        i32x2 ov = {o0, o1};
        __builtin_nontemporal_store(ov, (i32x2*)((int*)OUT + (size_t)n * 8 + l * 2));
    } else {
        half8 o;
#pragma unroll
        for (int j = 0; j < 8; ++j) o[j] = (half_t)(dv * acc[j]);
        __builtin_nontemporal_store(o, (half8*)((half_t*)OUT + (size_t)n * 32 + l * 8));
    }
}

// MFMA tail (unchanged; Y is fp16)
__global__ __launch_bounds__(256) void k_tail_mfma(
    const half_t* __restrict__ Y, const half_t* __restrict__ W2t, const float* __restrict__ b2,
    const half_t* __restrict__ Wm1t, const float* __restrict__ bm1,
    const float* __restrict__ Wm2, const float* __restrict__ bm2,
    const int* __restrict__ nn_p, float* __restrict__ out, int N, int n_graphs)
{
    __shared__ float gacc[32];
    __shared__ __align__(16) half_t Hb[4][16][72];
    const int tid = threadIdx.x;
    if (tid < 32) gacc[tid] = 0.f;
    __syncthreads();
    const int wid = tid >> 6, lane = tid & 63;
    const int quad = lane >> 4, n16 = lane & 15;
    const int n0 = blockIdx.x * 64 + wid * 16;
    if (n0 < N) {
        const int nrow = min(n0 + n16, N - 1);
        half8 a1 = *(const half8*)(Y + (size_t)nrow * 32 + quad * 8);
        f32x4 acc1[4];
#pragma unroll
        for (int t = 0; t < 4; ++t) {
            half8 bf = *(const half8*)(W2t + (size_t)(t * 16 + n16) * 32 + quad * 8);
            f32x4 z = {0.f, 0.f, 0.f, 0.f};
            acc1[t] = __builtin_amdgcn_mfma_f32_16x16x32_f16(a1, bf, z, 0, 0, 0);
        }
#pragma unroll
        for (int t = 0; t < 4; ++t) {
            int c = t * 16 + n16;
            float bb = b2[c];
#pragma unroll
            for (int r = 0; r < 4; ++r)
                Hb[wid][quad * 4 + r][c] = (half_t)fmaxf(acc1[t][r] + bb, 0.f);
        }
        half8 a2lo = *(const half8*)&Hb[wid][n16][quad * 8];
        half8 a2hi = *(const half8*)&Hb[wid][n16][32 + quad * 8];
        f32x4 acc2[4];
#pragma unroll
        for (int t = 0; t < 4; ++t) {
            half8 b0 = *(const half8*)(Wm1t + (size_t)(t * 16 + n16) * 64 + quad * 8);
            half8 b1 = *(const half8*)(Wm1t + (size_t)(t * 16 + n16) * 64 + 32 + quad * 8);
            f32x4 a = {0.f, 0.f, 0.f, 0.f};
            a = __builtin_amdgcn_mfma_f32_16x16x32_f16(a2lo, b0, a, 0, 0, 0);
            a = __builtin_amdgcn_mfma_f32_16x16x32_f16(a2hi, b1, a, 0, 0, 0);
            acc2[t] = a;
        }
        float vsum[4] = {0.f, 0.f, 0.f, 0.f};
#pragma unroll
        for (int t = 0; t < 4; ++t) {
            int c = t * 16 + n16;
            float bb = bm1[c], ww = Wm2[c];
#pragma unroll
            for (int r = 0; r < 4; ++r)
                vsum[r] += fmaxf(acc2[t][r] + bb, 0.f) * ww;
        }
#pragma unroll
        for (int m = 1; m < 16; m <<= 1) {
#pragma unroll
            for (int r = 0; r < 4; ++r) vsum[r] += __shfl_xor(vsum[r], m, 64);
        }
        if (n16 == 0) {
            const int nnv = nn_p[0];
            const float bm2v = bm2[0];
#pragma unroll
            for (int r = 0; r < 4; ++r) {
                int n = n0 + quad * 4 + r;
                if (n < N) {
                    int g = n / nnv;
                    if (g < 32) atomicAdd(&gacc[g], vsum[r] + bm2v);
                }
            }
        }
    }
    __syncthreads();
    if (tid < n_graphs && tid < 32) atomicAdd(&out[tid], gacc[tid] / (float)nn_p[0]);
}

// ---- fallback (atomic) path ----------------------------------------------
__global__ void k_zero_int(int* p, int n) {
    int i = blockIdx.x * blockDim.x + threadIdx.x;
    if (i < n) p[i] = 0;
}
__global__ void k_hist(const int* __restrict__ dst, int* __restrict__ deg, int E) {
    int e = blockIdx.x * blockDim.x + threadIdx.x;
    if (e < E) atomicAdd(&deg[dst[e]], 1);
}
__global__ void k_dinv(const int* __restrict__ deg, float* __restrict__ dinv, int n) {
    int i = blockIdx.x * blockDim.x + threadIdx.x;
    if (i < n) dinv[i] = rsqrtf(1.0f + (float)deg[i]);
}
__global__ __launch_bounds__(256) void k_gemm1f(
    const float* __restrict__ x, const float* __restrict__ W,
    const float* __restrict__ dinv, float* __restrict__ hs1, int N)
{
    __shared__ float Wl[128 * 32];
    __shared__ __align__(16) float Xl[8 * 132];
    const int tid = threadIdx.x;
    for (int i = tid; i < 128 * 32; i += 256) Wl[i] = W[i];
    const int node0 = blockIdx.x * 8;
    {
        int r = tid >> 5, c4 = tid & 31;
        int node = node0 + r;
        float4 v = make_float4(0.f, 0.f, 0.f, 0.f);
        if (node < N) v = ((const float4*)(x + (size_t)node * 128))[c4];
        *(float4*)&Xl[r * 132 + c4 * 4] = v;
    }
    __syncthreads();
    const int row = tid >> 5, f = tid & 31;
    float acc = 0.f;
#pragma unroll
    for (int k = 0; k < 128; k += 4) {
        float4 xv = *(const float4*)&Xl[row * 132 + k];
        acc += xv.x * Wl[(k + 0) * 32 + f];
        acc += xv.y * Wl[(k + 1) * 32 + f];
        acc += xv.z * Wl[(k + 2) * 32 + f];
        acc += xv.w * Wl[(k + 3) * 32 + f];
    }
    const int node = node0 + row;
    if (node < N) hs1[(size_t)node * 32 + f] = acc * dinv[node];
}
__global__ __launch_bounds__(256) void k_gemm2(
    const float* __restrict__ agg1, const float* __restrict__ W,
    const float* __restrict__ dinv, float* __restrict__ hs2, int N)
{
    __shared__ float Wl[32 * 64];
    __shared__ __align__(16) float Zl[4 * 36];
    const int tid = threadIdx.x;
    for (int i = tid; i < 32 * 64; i += 256) Wl[i] = W[i];
    const int node0 = blockIdx.x * 4;
    if (tid < 128) {
        int r = tid >> 5, c = tid & 31;
        int node = node0 + r;
        float v = 0.f;
        if (node < N) v = fmaxf(agg1[(size_t)node * 32 + c], 0.f);
        Zl[r * 36 + c] = v;
    }
    __syncthreads();
    const int row = tid >> 6, f = tid & 63;
    float acc = 0.f;
#pragma unroll
    for (int k = 0; k < 32; k += 4) {
        float4 zv = *(const float4*)&Zl[row * 36 + k];
        acc += zv.x * Wl[(k + 0) * 64 + f];
        acc += zv.y * Wl[(k + 1) * 64 + f];
        acc += zv.z * Wl[(k + 2) * 64 + f];
        acc += zv.w * Wl[(k + 3) * 64 + f];
    }
    int node = node0 + row;
    if (node < N) hs2[(size_t)node * 64 + f] = acc * dinv[node];
}
template <int F>
__global__ void k_agg_init(const float* __restrict__ hs, const float* __restrict__ b,
                           const float* __restrict__ dinv, float* __restrict__ agg, int N)
{
    long long t = (long long)blockIdx.x * blockDim.x + threadIdx.x;
    int n = (int)(t / F), f = (int)(t % F);
    if (n < N) agg[(size_t)n * F + f] = hs[(size_t)n * F + f] * dinv[n] + b[f];
}
template <int F>
__global__ void k_edge_atomic(const int* __restrict__ ei, const float* __restrict__ hs,
                              const float* __restrict__ dinv, float* __restrict__ agg, int E)
{
    long long tid = (long long)blockIdx.x * blockDim.x + threadIdx.x;
    int e = (int)(tid / F), f = (int)(tid % F);
    if (e < E) {
        int s = ei[e], d = ei[E + e];
        atomicAdd(&agg[(size_t)d * F + f], hs[(size_t)s * F + f] * dinv[d]);
    }
}
__global__ __launch_bounds__(256) void k_mlp(
    const float* __restrict__ agg2, const float* __restrict__ Wm1,
    const float* __restrict__ bm1, const float* __restrict__ Wm2,
    const float* __restrict__ bm2, float* __restrict__ vout, int N)
{
    __shared__ float Wl[64 * 64];
    __shared__ float W2l[64];
    __shared__ __align__(16) float Zl[4][64];
    const int tid = threadIdx.x;
    for (int i = tid; i < 64 * 64; i += 256) Wl[i] = Wm1[i];
    if (tid < 64) W2l[tid] = Wm2[tid];
    const int wid = tid >> 6, lane = tid & 63;
    const int node = blockIdx.x * 4 + wid;
    float zv = 0.f;
    if (node < N) zv = fmaxf(agg2[(size_t)node * 64 + lane], 0.f);
    Zl[wid][lane] = zv;
    __syncthreads();
    float t = bm1[lane];
#pragma unroll
    for (int k = 0; k < 64; k += 4) {
        float4 z4 = *(const float4*)&Zl[wid][k];
        t += z4.x * Wl[(k + 0) * 64 + lane];
        t += z4.y * Wl[(k + 1) * 64 + lane];
        t += z4.z * Wl[(k + 2) * 64 + lane];
        t += z4.w * Wl[(k + 3) * 64 + lane];
    }
    t = fmaxf(t, 0.f);
    float val = t * W2l[lane];
#pragma unroll
    for (int off = 32; off > 0; off >>= 1) val += __shfl_down(val, off, 64);
    if (lane == 0 && node < N) vout[node] = val + bm2[0];
}
__global__ void k_reduce(const float* __restrict__ v, const int* __restrict__ num_nodes_p,
                         float* out, int N, int n_graphs)
{
    __shared__ float acc[32];
    int tid = threadIdx.x;
    if (tid < n_graphs) acc[tid] = 0.f;
    __syncthreads();
    int i = blockIdx.x * blockDim.x + tid;
    int nn = num_nodes_p[0];
    if (i < N) {
        int g = i / nn;
        if (g < n_graphs) atomicAdd(&acc[g], v[i]);
    }
    __syncthreads();
    if (tid < n_graphs) atomicAdd(&out[tid], acc[tid] / (float)nn);
}
// ---------------------------------------------------------------------------

extern "C" void kernel_launch(void* const* d_in, const int* in_sizes, int n_in,
                              void* d_out, int out_size, void* d_ws, size_t ws_size,
                              hipStream_t stream)
{
    const float* x   = (const float*)d_in[0];
    const float* W1  = (const float*)d_in[1];
    const float* b1  = (const float*)d_in[2];
    const float* W2  = (const float*)d_in[3];
    const float* b2  = (const float*)d_in[4];
    const float* Wm1 = (const float*)d_in[5];
    const float* bm1 = (const float*)d_in[6];
    const float* Wm2 = (const float*)d_in[7];
    const float* bm2 = (const float*)d_in[8];
    const int*   ei  = (const int*)d_in[9];
    const int*   nn  = (const int*)d_in[10];
    const int N = in_sizes[0] / 128;
    const int E = in_sizes[9] / 2;
    float* out = (float*)d_out;

    const int NB = (N + BKN - 1) / BKN;
    const int nblk = (E + CHUNK - 1) / CHUNK;
    const long long T = (long long)NB * nblk;
    const int nb1 = (int)((T + 255) / 256);
    auto al4 = [](size_t v) { return (v + 3) & ~(size_t)3; };
    // ints: table T + S(T+1) + bsums 1024 + codes E + esrc E + row_start N+1
    //     + dinv N + hs8 8N + Zs8 8N + Y 16N + weights 5120 + align slop
    const size_t need_ints = al4(T) + al4(T + 1) + 1024 + al4(E) + al4(E)
                           + al4(N + 1) + al4(N) + 8ull * N + 8ull * N
                           + 16ull * N + 5120 + 64;
    const bool use_new = (N <= 131072) && (T <= 262144) && (nb1 <= 1024)
                       && (NB <= NBMAX) && (out_size <= 32)
                       && (ws_size >= need_ints * sizeof(int));

    if (use_new) {
        int* w = (int*)d_ws;
        int*    table     = w;                          w += al4(T);
        int*    S         = w;                          w += al4(T + 1);
        int*    bsums     = w;                          w += 1024;
        int*    codes     = w;                          w += al4(E);
        int*    esrc      = w;                          w += al4(E);
        int*    row_start = w;                          w += al4(N + 1);
        float*  dinv      = (float*)w;                  w += al4(N);
        int*    hs8       = w;                          w += 8ull * N;   // fp8 rows, 32 B
        int*    Zs8       = w;                          w += 8ull * N;   // fp8 rows
        half_t* Y         = (half_t*)w;                 w += 16ull * N;  // fp16 rows
        half_t* W1t       = (half_t*)w;                 // 4096 halves
        half_t* W2t       = W1t + 4096;                 // 2048 halves
        half_t* Wm1t      = W2t + 2048;                 // 4096 halves
        const int agrid = (N + 63) / 64;

        k_count_coarse<<<nblk, 256, 0, stream>>>(ei + E, table, E, nblk, NB);
        k_scan1<<<nb1, 256, 0, stream>>>(table, S, bsums, (int)T);
        k_scan2<<<1, 1024, 0, stream>>>(bsums, nb1);
        k_scan3<<<nb1, 256, 0, stream>>>(S, bsums, (int)T);
        k_scatter2<<<nblk, 256, 0, stream>>>(ei, S, codes, E, nblk, NB);
        k_fine<<<NB, 512, 0, stream>>>(codes, S, esrc, row_start, dinv, nblk, N, E, NB);
        k_prep<<<16, 256, 0, stream>>>(W1, W2, Wm1, W1t, W2t, Wm1t, out, out_size);
        k_gemm1_mfma<<<agrid, 256, 0, stream>>>(x, W1t, dinv, (unsigned char*)hs8, N);
        k_agg8<true><<<agrid, 256, 0, stream>>>(row_start, esrc, hs8, b1, dinv, Zs8, N);
        k_agg8<false><<<agrid, 256, 0, stream>>>(row_start, esrc, Zs8, b1, dinv, Y, N);
        k_tail_mfma<<<agrid, 256, 0, stream>>>(Y, W2t, b2, Wm1t, bm1, Wm2, bm2,
                                               nn, out, N, out_size);
    } else {
        // fallback: fp32 atomic scatter path
        const size_t Ns = (size_t)N;
        float* dinv = (float*)d_ws;
        float* B    = dinv + N;
        float* hs1  = B;
        float* agg1 = B + 32 * Ns;
        float* hs2  = B + 64 * Ns;
        float* agg2 = B + 128 * Ns;
        float* vtmp = B;
        int*   deg  = (int*)B;

        const int nb = (N + 255) / 256;
        k_zero_out<<<1, 64, 0, stream>>>(out, out_size);
        k_zero_int<<<nb, 256, 0, stream>>>(deg, N);
        k_hist<<<(E + 255) / 256, 256, 0, stream>>>(ei + E, deg, E);
        k_dinv<<<nb, 256, 0, stream>>>(deg, dinv, N);
        k_gemm1f<<<(N + 7) / 8, 256, 0, stream>>>(x, W1, dinv, hs1, N);
        {
            long long t = (long long)N * 32;
            k_agg_init<32><<<(unsigned)((t + 255) / 256), 256, 0, stream>>>(hs1, b1, dinv, agg1, N);
            t = (long long)E * 32;
            k_edge_atomic<32><<<(unsigned)((t + 255) / 256), 256, 0, stream>>>(ei, hs1, dinv, agg1, E);
        }
        k_gemm2<<<(N + 3) / 4, 256, 0, stream>>>(agg1, W2, dinv, hs2, N);
        {
            long long t = (long long)N * 64;
            k_agg_init<64><<<(unsigned)((t + 255) / 256), 256, 0, stream>>>(hs2, b2, dinv, agg2, N);
            t = (long long)E * 64;
            k_edge_atomic<64><<<(unsigned)((t + 255) / 256), 256, 0, stream>>>(ei, hs2, dinv, agg2, E);
        }
        k_mlp<<<(N + 3) / 4, 256, 0, stream>>>(agg2, Wm1, bm1, Wm2, bm2, vtmp, N);
        k_reduce<<<nb, 256, 0, stream>>>(vtmp, nn, out, N, out_size);
    }
}

// Round 12
// 245.303 us; speedup vs baseline: 1.2581x; 1.0699x over previous
//
#include <hip/hip_runtime.h>

// ---------------------------------------------------------------------------
// CriticNetwork: 2x GCNConv (relu) + MLP head + per-graph mean.
// Round 12 (= R11 + structural trims): scan3 folded into consumers, CHUNK
// 8192->4096 (2x sort blocks), MFMA tail fused into the layer-2 fp8 gather
// (Y passes through LDS, never global). fp8 e4m3 gather tables kept (R11 win).
// ---------------------------------------------------------------------------

typedef _Float16 half_t;
typedef __attribute__((ext_vector_type(8))) _Float16 half8;
typedef __attribute__((ext_vector_type(4))) float f32x4;
typedef __attribute__((ext_vector_type(2))) float f32x2;
typedef __attribute__((ext_vector_type(2))) int   i32x2;

#define CHUNK 4096    // edges per sort block
#define BKN   512     // nodes per coarse bucket
#define NBMAX 256     // max coarse buckets (N <= 131072)

__global__ void k_zero_out(float* out, int n) {
    int i = blockIdx.x * blockDim.x + threadIdx.x;
    if (i < n) out[i] = 0.0f;
}

// scanned S at flat index j (S holds block-local inclusive scan in S[j], j>=1;
// bsums holds exclusive-scanned block totals)
__device__ __forceinline__ int sfull(const int* S, const int* bs, int j) {
    return (j == 0) ? 0 : S[j] + bs[(j - 1) >> 8];
}

// ---- coarse counting sort ------------------------------------------------

__global__ __launch_bounds__(256) void k_count_coarse(
    const int* __restrict__ dst, int* __restrict__ table, int E, int nblk, int NB)
{
    __shared__ int cnt[NBMAX];
    const int tid = threadIdx.x;
    for (int i = tid; i < NB; i += 256) cnt[i] = 0;
    __syncthreads();
    const int base = blockIdx.x * CHUNK;
    const int lim = min(CHUNK, E - base);
    if (lim == CHUNK) {
        const int4* d4 = (const int4*)(dst + base);
        for (int i = tid; i < CHUNK / 4; i += 256) {
            int4 v = d4[i];
            atomicAdd(&cnt[v.x >> 9], 1);
            atomicAdd(&cnt[v.y >> 9], 1);
            atomicAdd(&cnt[v.z >> 9], 1);
            atomicAdd(&cnt[v.w >> 9], 1);
        }
    } else {
        for (int i = tid; i < lim; i += 256) atomicAdd(&cnt[dst[base + i] >> 9], 1);
    }
    __syncthreads();
    for (int b = tid; b < NB; b += 256) table[b * nblk + blockIdx.x] = cnt[b];
}

__global__ __launch_bounds__(256) void k_scan1(const int* __restrict__ cnts, int* __restrict__ S,
                                               int* __restrict__ bsums, int T) {
    __shared__ int sh[256];
    int t = threadIdx.x;
    int i = blockIdx.x * 256 + t;
    int v = (i < T) ? cnts[i] : 0;
    sh[t] = v;
    __syncthreads();
    for (int off = 1; off < 256; off <<= 1) {
        int tv = (t >= off) ? sh[t - off] : 0;
        __syncthreads();
        sh[t] += tv;
        __syncthreads();
    }
    if (i < T) S[i + 1] = sh[t];
    if (t == 255) bsums[blockIdx.x] = sh[255];
}

__global__ __launch_bounds__(1024) void k_scan2(int* bs, int nb) {
    __shared__ int sh[1024];
    int t = threadIdx.x;
    int v = (t < nb) ? bs[t] : 0;
    sh[t] = v;
    __syncthreads();
    for (int off = 1; off < 1024; off <<= 1) {
        int tv = (t >= off) ? sh[t - off] : 0;
        __syncthreads();
        sh[t] += tv;
        __syncthreads();
    }
    if (t < nb) bs[t] = sh[t] - v;  // exclusive
}

__global__ __launch_bounds__(256) void k_scatter2(
    const int* __restrict__ ei, const int* __restrict__ S, const int* __restrict__ bsums,
    int* __restrict__ codes, int E, int nblk, int NB)
{
    __shared__ int cur[NBMAX];
    const int tid = threadIdx.x;
    for (int i = tid; i < NB; i += 256)
        cur[i] = sfull(S, bsums, i * nblk + blockIdx.x);
    __syncthreads();
    const int base = blockIdx.x * CHUNK;
    const int lim = min(CHUNK, E - base);
    if (lim == CHUNK) {
        const int4* s4 = (const int4*)(ei + base);
        const int4* d4 = (const int4*)(ei + E + base);
        for (int i = tid; i < CHUNK / 4; i += 256) {
            int4 sv = s4[i], dv = d4[i];
            { int pos = atomicAdd(&cur[dv.x >> 9], 1); codes[pos] = ((dv.x & 511) << 17) | sv.x; }
            { int pos = atomicAdd(&cur[dv.y >> 9], 1); codes[pos] = ((dv.y & 511) << 17) | sv.y; }
            { int pos = atomicAdd(&cur[dv.z >> 9], 1); codes[pos] = ((dv.z & 511) << 17) | sv.z; }
            { int pos = atomicAdd(&cur[dv.w >> 9], 1); codes[pos] = ((dv.w & 511) << 17) | sv.w; }
        }
    } else {
        for (int i = tid; i < lim; i += 256) {
            int e = base + i;
            int s = ei[e], d = ei[E + e];
            int pos = atomicAdd(&cur[d >> 9], 1);
            codes[pos] = ((d & 511) << 17) | s;
        }
    }
}

__global__ __launch_bounds__(512) void k_fine(
    const int* __restrict__ codes, const int* __restrict__ S, const int* __restrict__ bsums,
    int* __restrict__ esrc, int* __restrict__ row_start,
    float* __restrict__ dinv, int nblk, int N, int E, int NB)
{
    __shared__ int cnt[BKN];
    __shared__ int sh[BKN];
    __shared__ int cur[BKN];
    const int tid = threadIdx.x;
    cnt[tid] = 0;
    __syncthreads();
    const int b = blockIdx.x;
    const int beg = sfull(S, bsums, b * nblk), end = sfull(S, bsums, (b + 1) * nblk);
    for (int e = beg + tid; e < end; e += 512) atomicAdd(&cnt[codes[e] >> 17], 1);
    __syncthreads();
    sh[tid] = cnt[tid];
    __syncthreads();
    for (int off = 1; off < 512; off <<= 1) {
        int tv = (tid >= off) ? sh[tid - off] : 0;
        __syncthreads();
        sh[tid] += tv;
        __syncthreads();
    }
    {
        int fs = beg + sh[tid] - cnt[tid];
        cur[tid] = fs;
        int n = b * BKN + tid;
        if (n < N) {
            row_start[n] = fs;
            dinv[n] = rsqrtf(1.0f + (float)cnt[tid]);
        }
    }
    if (b == NB - 1 && tid == 0) row_start[N] = E;
    __syncthreads();
    for (int e = beg + tid; e < end; e += 512) {
        int c = codes[e];
        int pos = atomicAdd(&cur[c >> 17], 1);
        esrc[pos] = c & 0x1FFFF;
    }
}

// ---- dense compute -------------------------------------------------------

// weights -> fp16 transposed; also zeroes out[]
__global__ __launch_bounds__(256) void k_prep(
    const float* __restrict__ W1, const float* __restrict__ W2, const float* __restrict__ Wm1,
    half_t* __restrict__ W1t, half_t* __restrict__ W2t, half_t* __restrict__ Wm1t,
    float* __restrict__ out, int out_n)
{
    int i = blockIdx.x * 256 + threadIdx.x;
    if (i < 128 * 32) { int k = i >> 5, c = i & 31; W1t[c * 128 + k] = (half_t)W1[i]; }
    if (i < 32 * 64)  { int k = i >> 6, c = i & 63; W2t[c * 32 + k]  = (half_t)W2[i]; }
    if (i < 64 * 64)  { int k = i >> 6, c = i & 63; Wm1t[c * 64 + k] = (half_t)Wm1[i]; }
    if (i < out_n) out[i] = 0.0f;
}

// hs1 = fp8( (x @ W1) * dinv ) via MFMA
__global__ __launch_bounds__(256) void k_gemm1_mfma(
    const float* __restrict__ x, const half_t* __restrict__ W1t,
    const float* __restrict__ dinv, unsigned char* __restrict__ hs8, int N)
{
    const int tid = threadIdx.x;
    const int wid = tid >> 6, lane = tid & 63;
    const int quad = lane >> 4, n16 = lane & 15;
    const int n0 = blockIdx.x * 64 + wid * 16;
    if (n0 >= N) return;
    const int nrow = min(n0 + n16, N - 1);
    const float* xr = x + (size_t)nrow * 128;
    f32x4 acc0 = {0.f, 0.f, 0.f, 0.f}, acc1 = {0.f, 0.f, 0.f, 0.f};
#pragma unroll
    for (int kc = 0; kc < 4; ++kc) {
        float4 f0 = *(const float4*)(xr + kc * 32 + quad * 8);
        float4 f1 = *(const float4*)(xr + kc * 32 + quad * 8 + 4);
        half8 a;
        a[0] = (half_t)f0.x; a[1] = (half_t)f0.y; a[2] = (half_t)f0.z; a[3] = (half_t)f0.w;
        a[4] = (half_t)f1.x; a[5] = (half_t)f1.y; a[6] = (half_t)f1.z; a[7] = (half_t)f1.w;
        half8 b0 = *(const half8*)(W1t + (size_t)n16 * 128 + kc * 32 + quad * 8);
        half8 b1 = *(const half8*)(W1t + (size_t)(16 + n16) * 128 + kc * 32 + quad * 8);
        acc0 = __builtin_amdgcn_mfma_f32_16x16x32_f16(a, b0, acc0, 0, 0, 0);
        acc1 = __builtin_amdgcn_mfma_f32_16x16x32_f16(a, b1, acc1, 0, 0, 0);
    }
#pragma unroll
    for (int r = 0; r < 4; ++r) {
        int n = n0 + quad * 4 + r;
        if (n < N) {
            float dv = dinv[n];
            int w0 = __builtin_amdgcn_cvt_pk_fp8_f32(acc0[r] * dv, 0.f, 0, false);
            int w1 = __builtin_amdgcn_cvt_pk_fp8_f32(acc1[r] * dv, 0.f, 0, false);
            hs8[(size_t)n * 32 + n16]      = (unsigned char)(w0 & 0xFF);
            hs8[(size_t)n * 32 + 16 + n16] = (unsigned char)(w1 & 0xFF);
        }
    }
}

__device__ __forceinline__ void unpack_acc8(i32x2 w, float* acc) {
    f32x2 p;
    p = __builtin_amdgcn_cvt_pk_f32_fp8(w.x, false); acc[0] += p.x; acc[1] += p.y;
    p = __builtin_amdgcn_cvt_pk_f32_fp8(w.x, true);  acc[2] += p.x; acc[3] += p.y;
    p = __builtin_amdgcn_cvt_pk_f32_fp8(w.y, false); acc[4] += p.x; acc[5] += p.y;
    p = __builtin_amdgcn_cvt_pk_f32_fp8(w.y, true);  acc[6] += p.x; acc[7] += p.y;
}

__device__ __forceinline__ void gather_row8(
    const int* __restrict__ row_start, const int* __restrict__ esrc,
    const int* __restrict__ IN, int n, int l, float* acc)
{
    const int beg = row_start[n], end = row_start[n + 1];
    {
        i32x2 ws_ = *(const i32x2*)(IN + (size_t)n * 8 + l * 2);  // self
        unpack_acc8(ws_, acc);
    }
    int e = beg;
    for (; e + 3 < end; e += 4) {
        int s0 = __builtin_nontemporal_load(esrc + e);
        int s1 = __builtin_nontemporal_load(esrc + e + 1);
        int s2 = __builtin_nontemporal_load(esrc + e + 2);
        int s3 = __builtin_nontemporal_load(esrc + e + 3);
        i32x2 w0 = *(const i32x2*)(IN + (size_t)s0 * 8 + l * 2);
        i32x2 w1 = *(const i32x2*)(IN + (size_t)s1 * 8 + l * 2);
        i32x2 w2 = *(const i32x2*)(IN + (size_t)s2 * 8 + l * 2);
        i32x2 w3 = *(const i32x2*)(IN + (size_t)s3 * 8 + l * 2);
        unpack_acc8(w0, acc);
        unpack_acc8(w1, acc);
        unpack_acc8(w2, acc);
        unpack_acc8(w3, acc);
    }
    for (; e < end; ++e) {
        int s = __builtin_nontemporal_load(esrc + e);
        i32x2 w = *(const i32x2*)(IN + (size_t)s * 8 + l * 2);
        unpack_acc8(w, acc);
    }
}

// layer-1 gather: OUT(fp8) = relu(dinv*acc + bias) * dinv
__global__ __launch_bounds__(256) void k_agg8_l1(
    const int* __restrict__ row_start, const int* __restrict__ esrc,
    const int* __restrict__ IN, const float* __restrict__ bias,
    const float* __restrict__ dinv, int* __restrict__ OUT, int N)
{
    const int tid = threadIdx.x;
    const int g = tid >> 2, l = tid & 3;       // 64 nodes x 4 lanes
    const int n = blockIdx.x * 64 + g;
    if (n >= N) return;
    float acc[8] = {0.f, 0.f, 0.f, 0.f, 0.f, 0.f, 0.f, 0.f};
    gather_row8(row_start, esrc, IN, n, l, acc);
    const float dv = dinv[n];
    float v[8];
#pragma unroll
    for (int j = 0; j < 8; ++j)
        v[j] = fmaxf(dv * acc[j] + bias[l * 8 + j], 0.f) * dv;
    int o0 = __builtin_amdgcn_cvt_pk_fp8_f32(v[0], v[1], 0, false);
    o0     = __builtin_amdgcn_cvt_pk_fp8_f32(v[2], v[3], o0, true);
    int o1 = __builtin_amdgcn_cvt_pk_fp8_f32(v[4], v[5], 0, false);
    o1     = __builtin_amdgcn_cvt_pk_fp8_f32(v[6], v[7], o1, true);
    i32x2 ov = {o0, o1};
    __builtin_nontemporal_store(ov, (i32x2*)(OUT + (size_t)n * 8 + l * 2));
}

// layer-2 gather fused with MFMA tail + per-graph mean. Y lives only in LDS.
__global__ __launch_bounds__(256) void k_agg8_tail(
    const int* __restrict__ row_start, const int* __restrict__ esrc,
    const int* __restrict__ IN, const float* __restrict__ dinv,
    const half_t* __restrict__ W2t, const float* __restrict__ b2,
    const half_t* __restrict__ Wm1t, const float* __restrict__ bm1,
    const float* __restrict__ Wm2, const float* __restrict__ bm2,
    const int* __restrict__ nn_p, float* __restrict__ out, int N, int n_graphs)
{
    __shared__ float gacc[32];
    __shared__ __align__(16) half_t Yb[64][40];     // 64 nodes x 32 (+8 pad)
    __shared__ __align__(16) half_t Hb[4][16][72];
    const int tid = threadIdx.x;
    if (tid < 32) gacc[tid] = 0.f;
    // ---- gather phase: 64 nodes x 4 lanes ----
    {
        const int g = tid >> 2, l = tid & 3;
        const int n = blockIdx.x * 64 + g;
        if (n < N) {
            float acc[8] = {0.f, 0.f, 0.f, 0.f, 0.f, 0.f, 0.f, 0.f};
            gather_row8(row_start, esrc, IN, n, l, acc);
            const float dv = dinv[n];
#pragma unroll
            for (int j = 0; j < 8; ++j) Yb[g][l * 8 + j] = (half_t)(dv * acc[j]);
        } else {
#pragma unroll
            for (int j = 0; j < 8; ++j) Yb[g][l * 8 + j] = (half_t)0.f;
        }
    }
    __syncthreads();
    // ---- tail phase: wave wid handles 16 nodes ----
    const int wid = tid >> 6, lane = tid & 63;
    const int quad = lane >> 4, n16 = lane & 15;
    const int n0 = blockIdx.x * 64 + wid * 16;
    if (n0 < N) {
        half8 a1 = *(const half8*)&Yb[wid * 16 + n16][quad * 8];
        f32x4 acc1[4];
#pragma unroll
        for (int t = 0; t < 4; ++t) {
            half8 bf = *(const half8*)(W2t + (size_t)(t * 16 + n16) * 32 + quad * 8);
            f32x4 z = {0.f, 0.f, 0.f, 0.f};
            acc1[t] = __builtin_amdgcn_mfma_f32_16x16x32_f16(a1, bf, z, 0, 0, 0);
        }
#pragma unroll
        for (int t = 0; t < 4; ++t) {
            int c = t * 16 + n16;
            float bb = b2[c];
#pragma unroll
            for (int r = 0; r < 4; ++r)
                Hb[wid][quad * 4 + r][c] = (half_t)fmaxf(acc1[t][r] + bb, 0.f);
        }
        half8 a2lo = *(const half8*)&Hb[wid][n16][quad * 8];
        half8 a2hi = *(const half8*)&Hb[wid][n16][32 + quad * 8];
        f32x4 acc2[4];
#pragma unroll
        for (int t = 0; t < 4; ++t) {
            half8 b0 = *(const half8*)(Wm1t + (size_t)(t * 16 + n16) * 64 + quad * 8);
            half8 b1 = *(const half8*)(Wm1t + (size_t)(t * 16 + n16) * 64 + 32 + quad * 8);
            f32x4 a = {0.f, 0.f, 0.f, 0.f};
            a = __builtin_amdgcn_mfma_f32_16x16x32_f16(a2lo, b0, a, 0, 0, 0);
            a = __builtin_amdgcn_mfma_f32_16x16x32_f16(a2hi, b1, a, 0, 0, 0);
            acc2[t] = a;
        }
        float vsum[4] = {0.f, 0.f, 0.f, 0.f};
#pragma unroll
        for (int t = 0; t < 4; ++t) {
            int c = t * 16 + n16;
            float bb = bm1[c], ww = Wm2[c];
#pragma unroll
            for (int r = 0; r < 4; ++r)
                vsum[r] += fmaxf(acc2[t][r] + bb, 0.f) * ww;
        }
#pragma unroll
        for (int m = 1; m < 16; m <<= 1) {
#pragma unroll
            for (int r = 0; r < 4; ++r) vsum[r] += __shfl_xor(vsum[r], m, 64);
        }
        if (n16 == 0) {
            const int nnv = nn_p[0];
            const float bm2v = bm2[0];
#pragma unroll
            for (int r = 0; r < 4; ++r) {
                int n = n0 + quad * 4 + r;
                if (n < N) {
                    int g = n / nnv;
                    if (g < 32) atomicAdd(&gacc[g], vsum[r] + bm2v);
                }
            }
        }
    }
    __syncthreads();
    if (tid < n_graphs && tid < 32) atomicAdd(&out[tid], gacc[tid] / (float)nn_p[0]);
}

// ---- fallback (atomic) path ----------------------------------------------
__global__ void k_zero_int(int* p, int n) {
    int i = blockIdx.x * blockDim.x + threadIdx.x;
    if (i < n) p[i] = 0;
}
__global__ void k_hist(const int* __restrict__ dst, int* __restrict__ deg, int E) {
    int e = blockIdx.x * blockDim.x + threadIdx.x;
    if (e < E) atomicAdd(&deg[dst[e]], 1);
}
__global__ void k_dinv(const int* __restrict__ deg, float* __restrict__ dinv, int n) {
    int i = blockIdx.x * blockDim.x + threadIdx.x;
    if (i < n) dinv[i] = rsqrtf(1.0f + (float)deg[i]);
}
__global__ __launch_bounds__(256) void k_gemm1f(
    const float* __restrict__ x, const float* __restrict__ W,
    const float* __restrict__ dinv, float* __restrict__ hs1, int N)
{
    __shared__ float Wl[128 * 32];
    __shared__ __align__(16) float Xl[8 * 132];
    const int tid = threadIdx.x;
    for (int i = tid; i < 128 * 32; i += 256) Wl[i] = W[i];
    const int node0 = blockIdx.x * 8;
    {
        int r = tid >> 5, c4 = tid & 31;
        int node = node0 + r;
        float4 v = make_float4(0.f, 0.f, 0.f, 0.f);
        if (node < N) v = ((const float4*)(x + (size_t)node * 128))[c4];
        *(float4*)&Xl[r * 132 + c4 * 4] = v;
    }
    __syncthreads();
    const int row = tid >> 5, f = tid & 31;
    float acc = 0.f;
#pragma unroll
    for (int k = 0; k < 128; k += 4) {
        float4 xv = *(const float4*)&Xl[row * 132 + k];
        acc += xv.x * Wl[(k + 0) * 32 + f];
        acc += xv.y * Wl[(k + 1) * 32 + f];
        acc += xv.z * Wl[(k + 2) * 32 + f];
        acc += xv.w * Wl[(k + 3) * 32 + f];
    }
    const int node = node0 + row;
    if (node < N) hs1[(size_t)node * 32 + f] = acc * dinv[node];
}
__global__ __launch_bounds__(256) void k_gemm2(
    const float* __restrict__ agg1, const float* __restrict__ W,
    const float* __restrict__ dinv, float* __restrict__ hs2, int N)
{
    __shared__ float Wl[32 * 64];
    __shared__ __align__(16) float Zl[4 * 36];
    const int tid = threadIdx.x;
    for (int i = tid; i < 32 * 64; i += 256) Wl[i] = W[i];
    const int node0 = blockIdx.x * 4;
    if (tid < 128) {
        int r = tid >> 5, c = tid & 31;
        int node = node0 + r;
        float v = 0.f;
        if (node < N) v = fmaxf(agg1[(size_t)node * 32 + c], 0.f);
        Zl[r * 36 + c] = v;
    }
    __syncthreads();
    const int row = tid >> 6, f = tid & 63;
    float acc = 0.f;
#pragma unroll
    for (int k = 0; k < 32; k += 4) {
        float4 zv = *(const float4*)&Zl[row * 36 + k];
        acc += zv.x * Wl[(k + 0) * 64 + f];
        acc += zv.y * Wl[(k + 1) * 64 + f];
        acc += zv.z * Wl[(k + 2) * 64 + f];
        acc += zv.w * Wl[(k + 3) * 64 + f];
    }
    int node = node0 + row;
    if (node < N) hs2[(size_t)node * 64 + f] = acc * dinv[node];
}
template <int F>
__global__ void k_agg_init(const float* __restrict__ hs, const float* __restrict__ b,
                           const float* __restrict__ dinv, float* __restrict__ agg, int N)
{
    long long t = (long long)blockIdx.x * blockDim.x + threadIdx.x;
    int n = (int)(t / F), f = (int)(t % F);
    if (n < N) agg[(size_t)n * F + f] = hs[(size_t)n * F + f] * dinv[n] + b[f];
}
template <int F>
__global__ void k_edge_atomic(const int* __restrict__ ei, const float* __restrict__ hs,
                              const float* __restrict__ dinv, float* __restrict__ agg, int E)
{
    long long tid = (long long)blockIdx.x * blockDim.x + threadIdx.x;
    int e = (int)(tid / F), f = (int)(tid % F);
    if (e < E) {
        int s = ei[e], d = ei[E + e];
        atomicAdd(&agg[(size_t)d * F + f], hs[(size_t)s * F + f] * dinv[d]);
    }
}
__global__ __launch_bounds__(256) void k_mlp(
    const float* __restrict__ agg2, const float* __restrict__ Wm1,
    const float* __restrict__ bm1, const float* __restrict__ Wm2,
    const float* __restrict__ bm2, float* __restrict__ vout, int N)
{
    __shared__ float Wl[64 * 64];
    __shared__ float W2l[64];
    __shared__ __align__(16) float Zl[4][64];
    const int tid = threadIdx.x;
    for (int i = tid; i < 64 * 64; i += 256) Wl[i] = Wm1[i];
    if (tid < 64) W2l[tid] = Wm2[tid];
    const int wid = tid >> 6, lane = tid & 63;
    const int node = blockIdx.x * 4 + wid;
    float zv = 0.f;
    if (node < N) zv = fmaxf(agg2[(size_t)node * 64 + lane], 0.f);
    Zl[wid][lane] = zv;
    __syncthreads();
    float t = bm1[lane];
#pragma unroll
    for (int k = 0; k < 64; k += 4) {
        float4 z4 = *(const float4*)&Zl[wid][k];
        t += z4.x * Wl[(k + 0) * 64 + lane];
        t += z4.y * Wl[(k + 1) * 64 + lane];
        t += z4.z * Wl[(k + 2) * 64 + lane];
        t += z4.w * Wl[(k + 3) * 64 + lane];
    }
    t = fmaxf(t, 0.f);
    float val = t * W2l[lane];
#pragma unroll
    for (int off = 32; off > 0; off >>= 1) val += __shfl_down(val, off, 64);
    if (lane == 0 && node < N) vout[node] = val + bm2[0];
}
__global__ void k_reduce(const float* __restrict__ v, const int* __restrict__ num_nodes_p,
                         float* out, int N, int n_graphs)
{
    __shared__ float acc[32];
    int tid = threadIdx.x;
    if (tid < n_graphs) acc[tid] = 0.f;
    __syncthreads();
    int i = blockIdx.x * blockDim.x + tid;
    int nn = num_nodes_p[0];
    if (i < N) {
        int g = i / nn;
        if (g < n_graphs) atomicAdd(&acc[g], v[i]);
    }
    __syncthreads();
    if (tid < n_graphs) atomicAdd(&out[tid], acc[tid] / (float)nn);
}
// ---------------------------------------------------------------------------

extern "C" void kernel_launch(void* const* d_in, const int* in_sizes, int n_in,
                              void* d_out, int out_size, void* d_ws, size_t ws_size,
                              hipStream_t stream)
{
    const float* x   = (const float*)d_in[0];
    const float* W1  = (const float*)d_in[1];
    const float* b1  = (const float*)d_in[2];
    const float* W2  = (const float*)d_in[3];
    const float* b2  = (const float*)d_in[4];
    const float* Wm1 = (const float*)d_in[5];
    const float* bm1 = (const float*)d_in[6];
    const float* Wm2 = (const float*)d_in[7];
    const float* bm2 = (const float*)d_in[8];
    const int*   ei  = (const int*)d_in[9];
    const int*   nn  = (const int*)d_in[10];
    const int N = in_sizes[0] / 128;
    const int E = in_sizes[9] / 2;
    float* out = (float*)d_out;

    const int NB = (N + BKN - 1) / BKN;
    const int nblk = (E + CHUNK - 1) / CHUNK;
    const long long T = (long long)NB * nblk;
    const int nb1 = (int)((T + 255) / 256);
    auto al4 = [](size_t v) { return (v + 3) & ~(size_t)3; };
    const size_t need_ints = al4(T) + al4(T + 1) + 1024 + al4(E) + al4(E)
                           + al4(N + 1) + al4(N) + 8ull * N + 8ull * N
                           + 5120 + 64;
    const bool use_new = (N <= 131072) && (T <= 262144) && (nb1 <= 1024)
                       && (NB <= NBMAX) && (out_size <= 32)
                       && (ws_size >= need_ints * sizeof(int));

    if (use_new) {
        int* w = (int*)d_ws;
        int*    table     = w;                          w += al4(T);
        int*    S         = w;                          w += al4(T + 1);
        int*    bsums     = w;                          w += 1024;
        int*    codes     = w;                          w += al4(E);
        int*    esrc      = w;                          w += al4(E);
        int*    row_start = w;                          w += al4(N + 1);
        float*  dinv      = (float*)w;                  w += al4(N);
        int*    hs8       = w;                          w += 8ull * N;   // fp8 rows, 32 B
        int*    Zs8       = w;                          w += 8ull * N;   // fp8 rows
        half_t* W1t       = (half_t*)w;                 // 4096 halves
        half_t* W2t       = W1t + 4096;                 // 2048 halves
        half_t* Wm1t      = W2t + 2048;                 // 4096 halves
        const int agrid = (N + 63) / 64;

        k_count_coarse<<<nblk, 256, 0, stream>>>(ei + E, table, E, nblk, NB);
        k_scan1<<<nb1, 256, 0, stream>>>(table, S, bsums, (int)T);
        k_scan2<<<1, 1024, 0, stream>>>(bsums, nb1);
        k_scatter2<<<nblk, 256, 0, stream>>>(ei, S, bsums, codes, E, nblk, NB);
        k_fine<<<NB, 512, 0, stream>>>(codes, S, bsums, esrc, row_start, dinv, nblk, N, E, NB);
        k_prep<<<16, 256, 0, stream>>>(W1, W2, Wm1, W1t, W2t, Wm1t, out, out_size);
        k_gemm1_mfma<<<agrid, 256, 0, stream>>>(x, W1t, dinv, (unsigned char*)hs8, N);
        k_agg8_l1<<<agrid, 256, 0, stream>>>(row_start, esrc, hs8, b1, dinv, Zs8, N);
        k_agg8_tail<<<agrid, 256, 0, stream>>>(row_start, esrc, Zs8, dinv,
                                               W2t, b2, Wm1t, bm1, Wm2, bm2,
                                               nn, out, N, out_size);
    } else {
        // fallback: fp32 atomic scatter path
        const size_t Ns = (size_t)N;
        float* dinv = (float*)d_ws;
        float* B    = dinv + N;
        float* hs1  = B;
        float* agg1 = B + 32 * Ns;
        float* hs2  = B + 64 * Ns;
        float* agg2 = B + 128 * Ns;
        float* vtmp = B;
        int*   deg  = (int*)B;

        const int nb = (N + 255) / 256;
        k_zero_out<<<1, 64, 0, stream>>>(out, out_size);
        k_zero_int<<<nb, 256, 0, stream>>>(deg, N);
        k_hist<<<(E + 255) / 256, 256, 0, stream>>>(ei + E, deg, E);
        k_dinv<<<nb, 256, 0, stream>>>(deg, dinv, N);
        k_gemm1f<<<(N + 7) / 8, 256, 0, stream>>>(x, W1, dinv, hs1, N);
        {
            long long t = (long long)N * 32;
            k_agg_init<32><<<(unsigned)((t + 255) / 256), 256, 0, stream>>>(hs1, b1, dinv, agg1, N);
            t = (long long)E * 32;
            k_edge_atomic<32><<<(unsigned)((t + 255) / 256), 256, 0, stream>>>(ei, hs1, dinv, agg1, E);
        }
        k_gemm2<<<(N + 3) / 4, 256, 0, stream>>>(agg1, W2, dinv, hs2, N);
        {
            long long t = (long long)N * 64;
            k_agg_init<64><<<(unsigned)((t + 255) / 256), 256, 0, stream>>>(hs2, b2, dinv, agg2, N);
            t = (long long)E * 64;
            k_edge_atomic<64><<<(unsigned)((t + 255) / 256), 256, 0, stream>>>(ei, hs2, dinv, agg2, E);
        }
        k_mlp<<<(N + 3) / 4, 256, 0, stream>>>(agg2, Wm1, bm1, Wm2, bm2, vtmp, N);
        k_reduce<<<nb, 256, 0, stream>>>(vtmp, nn, out, N, out_size);
    }
}

// Round 13
// 241.160 us; speedup vs baseline: 1.2797x; 1.0172x over previous
//
#include <hip/hip_runtime.h>

// ---------------------------------------------------------------------------
// CriticNetwork: 2x GCNConv (relu) + MLP head + per-graph mean.
// Round 13 (= R12 + wide gather): fp8 gather uses 16 B loads, 2 lanes/node,
// 128 nodes/block (halves L1/TA request count — R12 showed request-rate bound,
// FETCH 31 MB but 49 us). Fused tail runs 2x 16-node MFMA tiles per wave.
// ---------------------------------------------------------------------------

typedef _Float16 half_t;
typedef __attribute__((ext_vector_type(8))) _Float16 half8;
typedef __attribute__((ext_vector_type(4))) float f32x4;
typedef __attribute__((ext_vector_type(2))) float f32x2;
typedef __attribute__((ext_vector_type(4))) int   i32x4;

#define CHUNK 4096    // edges per sort block
#define BKN   512     // nodes per coarse bucket
#define NBMAX 256     // max coarse buckets (N <= 131072)

__global__ void k_zero_out(float* out, int n) {
    int i = blockIdx.x * blockDim.x + threadIdx.x;
    if (i < n) out[i] = 0.0f;
}

// scanned S at flat index j
__device__ __forceinline__ int sfull(const int* S, const int* bs, int j) {
    return (j == 0) ? 0 : S[j] + bs[(j - 1) >> 8];
}

// ---- coarse counting sort ------------------------------------------------

__global__ __launch_bounds__(256) void k_count_coarse(
    const int* __restrict__ dst, int* __restrict__ table, int E, int nblk, int NB)
{
    __shared__ int cnt[NBMAX];
    const int tid = threadIdx.x;
    for (int i = tid; i < NB; i += 256) cnt[i] = 0;
    __syncthreads();
    const int base = blockIdx.x * CHUNK;
    const int lim = min(CHUNK, E - base);
    if (lim == CHUNK) {
        const int4* d4 = (const int4*)(dst + base);
        for (int i = tid; i < CHUNK / 4; i += 256) {
            int4 v = d4[i];
            atomicAdd(&cnt[v.x >> 9], 1);
            atomicAdd(&cnt[v.y >> 9], 1);
            atomicAdd(&cnt[v.z >> 9], 1);
            atomicAdd(&cnt[v.w >> 9], 1);
        }
    } else {
        for (int i = tid; i < lim; i += 256) atomicAdd(&cnt[dst[base + i] >> 9], 1);
    }
    __syncthreads();
    for (int b = tid; b < NB; b += 256) table[b * nblk + blockIdx.x] = cnt[b];
}

__global__ __launch_bounds__(256) void k_scan1(const int* __restrict__ cnts, int* __restrict__ S,
                                               int* __restrict__ bsums, int T) {
    __shared__ int sh[256];
    int t = threadIdx.x;
    int i = blockIdx.x * 256 + t;
    int v = (i < T) ? cnts[i] : 0;
    sh[t] = v;
    __syncthreads();
    for (int off = 1; off < 256; off <<= 1) {
        int tv = (t >= off) ? sh[t - off] : 0;
        __syncthreads();
        sh[t] += tv;
        __syncthreads();
    }
    if (i < T) S[i + 1] = sh[t];
    if (t == 255) bsums[blockIdx.x] = sh[255];
}

__global__ __launch_bounds__(1024) void k_scan2(int* bs, int nb) {
    __shared__ int sh[1024];
    int t = threadIdx.x;
    int v = (t < nb) ? bs[t] : 0;
    sh[t] = v;
    __syncthreads();
    for (int off = 1; off < 1024; off <<= 1) {
        int tv = (t >= off) ? sh[t - off] : 0;
        __syncthreads();
        sh[t] += tv;
        __syncthreads();
    }
    if (t < nb) bs[t] = sh[t] - v;  // exclusive
}

__global__ __launch_bounds__(256) void k_scatter2(
    const int* __restrict__ ei, const int* __restrict__ S, const int* __restrict__ bsums,
    int* __restrict__ codes, int E, int nblk, int NB)
{
    __shared__ int cur[NBMAX];
    const int tid = threadIdx.x;
    for (int i = tid; i < NB; i += 256)
        cur[i] = sfull(S, bsums, i * nblk + blockIdx.x);
    __syncthreads();
    const int base = blockIdx.x * CHUNK;
    const int lim = min(CHUNK, E - base);
    if (lim == CHUNK) {
        const int4* s4 = (const int4*)(ei + base);
        const int4* d4 = (const int4*)(ei + E + base);
        for (int i = tid; i < CHUNK / 4; i += 256) {
            int4 sv = s4[i], dv = d4[i];
            { int pos = atomicAdd(&cur[dv.x >> 9], 1); codes[pos] = ((dv.x & 511) << 17) | sv.x; }
            { int pos = atomicAdd(&cur[dv.y >> 9], 1); codes[pos] = ((dv.y & 511) << 17) | sv.y; }
            { int pos = atomicAdd(&cur[dv.z >> 9], 1); codes[pos] = ((dv.z & 511) << 17) | sv.z; }
            { int pos = atomicAdd(&cur[dv.w >> 9], 1); codes[pos] = ((dv.w & 511) << 17) | sv.w; }
        }
    } else {
        for (int i = tid; i < lim; i += 256) {
            int e = base + i;
            int s = ei[e], d = ei[E + e];
            int pos = atomicAdd(&cur[d >> 9], 1);
            codes[pos] = ((d & 511) << 17) | s;
        }
    }
}

__global__ __launch_bounds__(512) void k_fine(
    const int* __restrict__ codes, const int* __restrict__ S, const int* __restrict__ bsums,
    int* __restrict__ esrc, int* __restrict__ row_start,
    float* __restrict__ dinv, int nblk, int N, int E, int NB)
{
    __shared__ int cnt[BKN];
    __shared__ int sh[BKN];
    __shared__ int cur[BKN];
    const int tid = threadIdx.x;
    cnt[tid] = 0;
    __syncthreads();
    const int b = blockIdx.x;
    const int beg = sfull(S, bsums, b * nblk), end = sfull(S, bsums, (b + 1) * nblk);
    for (int e = beg + tid; e < end; e += 512) atomicAdd(&cnt[codes[e] >> 17], 1);
    __syncthreads();
    sh[tid] = cnt[tid];
    __syncthreads();
    for (int off = 1; off < 512; off <<= 1) {
        int tv = (tid >= off) ? sh[tid - off] : 0;
        __syncthreads();
        sh[tid] += tv;
        __syncthreads();
    }
    {
        int fs = beg + sh[tid] - cnt[tid];
        cur[tid] = fs;
        int n = b * BKN + tid;
        if (n < N) {
            row_start[n] = fs;
            dinv[n] = rsqrtf(1.0f + (float)cnt[tid]);
        }
    }
    if (b == NB - 1 && tid == 0) row_start[N] = E;
    __syncthreads();
    for (int e = beg + tid; e < end; e += 512) {
        int c = codes[e];
        int pos = atomicAdd(&cur[c >> 17], 1);
        esrc[pos] = c & 0x1FFFF;
    }
}

// ---- dense compute -------------------------------------------------------

// weights -> fp16 transposed; also zeroes out[]
__global__ __launch_bounds__(256) void k_prep(
    const float* __restrict__ W1, const float* __restrict__ W2, const float* __restrict__ Wm1,
    half_t* __restrict__ W1t, half_t* __restrict__ W2t, half_t* __restrict__ Wm1t,
    float* __restrict__ out, int out_n)
{
    int i = blockIdx.x * 256 + threadIdx.x;
    if (i < 128 * 32) { int k = i >> 5, c = i & 31; W1t[c * 128 + k] = (half_t)W1[i]; }
    if (i < 32 * 64)  { int k = i >> 6, c = i & 63; W2t[c * 32 + k]  = (half_t)W2[i]; }
    if (i < 64 * 64)  { int k = i >> 6, c = i & 63; Wm1t[c * 64 + k] = (half_t)Wm1[i]; }
    if (i < out_n) out[i] = 0.0f;
}

// hs1 = fp8( (x @ W1) * dinv ) via MFMA
__global__ __launch_bounds__(256) void k_gemm1_mfma(
    const float* __restrict__ x, const half_t* __restrict__ W1t,
    const float* __restrict__ dinv, unsigned char* __restrict__ hs8, int N)
{
    const int tid = threadIdx.x;
    const int wid = tid >> 6, lane = tid & 63;
    const int quad = lane >> 4, n16 = lane & 15;
    const int n0 = blockIdx.x * 64 + wid * 16;
    if (n0 >= N) return;
    const int nrow = min(n0 + n16, N - 1);
    const float* xr = x + (size_t)nrow * 128;
    f32x4 acc0 = {0.f, 0.f, 0.f, 0.f}, acc1 = {0.f, 0.f, 0.f, 0.f};
#pragma unroll
    for (int kc = 0; kc < 4; ++kc) {
        float4 f0 = *(const float4*)(xr + kc * 32 + quad * 8);
        float4 f1 = *(const float4*)(xr + kc * 32 + quad * 8 + 4);
        half8 a;
        a[0] = (half_t)f0.x; a[1] = (half_t)f0.y; a[2] = (half_t)f0.z; a[3] = (half_t)f0.w;
        a[4] = (half_t)f1.x; a[5] = (half_t)f1.y; a[6] = (half_t)f1.z; a[7] = (half_t)f1.w;
        half8 b0 = *(const half8*)(W1t + (size_t)n16 * 128 + kc * 32 + quad * 8);
        half8 b1 = *(const half8*)(W1t + (size_t)(16 + n16) * 128 + kc * 32 + quad * 8);
        acc0 = __builtin_amdgcn_mfma_f32_16x16x32_f16(a, b0, acc0, 0, 0, 0);
        acc1 = __builtin_amdgcn_mfma_f32_16x16x32_f16(a, b1, acc1, 0, 0, 0);
    }
#pragma unroll
    for (int r = 0; r < 4; ++r) {
        int n = n0 + quad * 4 + r;
        if (n < N) {
            float dv = dinv[n];
            int w0 = __builtin_amdgcn_cvt_pk_fp8_f32(acc0[r] * dv, 0.f, 0, false);
            int w1 = __builtin_amdgcn_cvt_pk_fp8_f32(acc1[r] * dv, 0.f, 0, false);
            hs8[(size_t)n * 32 + n16]      = (unsigned char)(w0 & 0xFF);
            hs8[(size_t)n * 32 + 16 + n16] = (unsigned char)(w1 & 0xFF);
        }
    }
}

__device__ __forceinline__ void unpack_dw(int w, float* acc) {
    f32x2 p;
    p = __builtin_amdgcn_cvt_pk_f32_fp8(w, false); acc[0] += p.x; acc[1] += p.y;
    p = __builtin_amdgcn_cvt_pk_f32_fp8(w, true);  acc[2] += p.x; acc[3] += p.y;
}

__device__ __forceinline__ void unpack_acc16(i32x4 w, float* acc) {
    unpack_dw(w.x, acc + 0);
    unpack_dw(w.y, acc + 4);
    unpack_dw(w.z, acc + 8);
    unpack_dw(w.w, acc + 12);
}

// gather half a row (16 B = 16 fp8 values) per lane; 2 lanes/node
__device__ __forceinline__ void gather_row16(
    const int* __restrict__ row_start, const int* __restrict__ esrc,
    const int* __restrict__ IN, int n, int l, float* acc)
{
    const int beg = row_start[n], end = row_start[n + 1];
    {
        i32x4 ws_ = *(const i32x4*)(IN + (size_t)n * 8 + l * 4);  // self
        unpack_acc16(ws_, acc);
    }
    int e = beg;
    for (; e + 3 < end; e += 4) {
        int s0 = __builtin_nontemporal_load(esrc + e);
        int s1 = __builtin_nontemporal_load(esrc + e + 1);
        int s2 = __builtin_nontemporal_load(esrc + e + 2);
        int s3 = __builtin_nontemporal_load(esrc + e + 3);
        i32x4 w0 = *(const i32x4*)(IN + (size_t)s0 * 8 + l * 4);
        i32x4 w1 = *(const i32x4*)(IN + (size_t)s1 * 8 + l * 4);
        i32x4 w2 = *(const i32x4*)(IN + (size_t)s2 * 8 + l * 4);
        i32x4 w3 = *(const i32x4*)(IN + (size_t)s3 * 8 + l * 4);
        unpack_acc16(w0, acc);
        unpack_acc16(w1, acc);
        unpack_acc16(w2, acc);
        unpack_acc16(w3, acc);
    }
    for (; e < end; ++e) {
        int s = __builtin_nontemporal_load(esrc + e);
        i32x4 w = *(const i32x4*)(IN + (size_t)s * 8 + l * 4);
        unpack_acc16(w, acc);
    }
}

// layer-1 gather: OUT(fp8) = relu(dinv*acc + bias) * dinv. 128 nodes/block.
__global__ __launch_bounds__(256) void k_agg8_l1(
    const int* __restrict__ row_start, const int* __restrict__ esrc,
    const int* __restrict__ IN, const float* __restrict__ bias,
    const float* __restrict__ dinv, int* __restrict__ OUT, int N)
{
    const int tid = threadIdx.x;
    const int g = tid >> 1, l = tid & 1;       // 128 nodes x 2 lanes
    const int n = blockIdx.x * 128 + g;
    if (n >= N) return;
    float acc[16];
#pragma unroll
    for (int j = 0; j < 16; ++j) acc[j] = 0.f;
    gather_row16(row_start, esrc, IN, n, l, acc);
    const float dv = dinv[n];
    float v[16];
#pragma unroll
    for (int j = 0; j < 16; ++j)
        v[j] = fmaxf(dv * acc[j] + bias[l * 16 + j], 0.f) * dv;
    i32x4 o;
    {
        int d;
        d = __builtin_amdgcn_cvt_pk_fp8_f32(v[0],  v[1],  0, false);
        d = __builtin_amdgcn_cvt_pk_fp8_f32(v[2],  v[3],  d, true);  o.x = d;
        d = __builtin_amdgcn_cvt_pk_fp8_f32(v[4],  v[5],  0, false);
        d = __builtin_amdgcn_cvt_pk_fp8_f32(v[6],  v[7],  d, true);  o.y = d;
        d = __builtin_amdgcn_cvt_pk_fp8_f32(v[8],  v[9],  0, false);
        d = __builtin_amdgcn_cvt_pk_fp8_f32(v[10], v[11], d, true);  o.z = d;
        d = __builtin_amdgcn_cvt_pk_fp8_f32(v[12], v[13], 0, false);
        d = __builtin_amdgcn_cvt_pk_fp8_f32(v[14], v[15], d, true);  o.w = d;
    }
    __builtin_nontemporal_store(o, (i32x4*)(OUT + (size_t)n * 8 + l * 4));
}

// layer-2 gather fused with MFMA tail + per-graph mean. 128 nodes/block;
// Y lives only in LDS; each wave runs two 16-node MFMA tiles.
__global__ __launch_bounds__(256) void k_agg8_tail(
    const int* __restrict__ row_start, const int* __restrict__ esrc,
    const int* __restrict__ IN, const float* __restrict__ dinv,
    const half_t* __restrict__ W2t, const float* __restrict__ b2,
    const half_t* __restrict__ Wm1t, const float* __restrict__ bm1,
    const float* __restrict__ Wm2, const float* __restrict__ bm2,
    const int* __restrict__ nn_p, float* __restrict__ out, int N, int n_graphs)
{
    __shared__ float gacc[32];
    __shared__ __align__(16) half_t Yb[128][40];    // 128 nodes x 32 (+8 pad)
    __shared__ __align__(16) half_t Hb[4][16][72];
    const int tid = threadIdx.x;
    if (tid < 32) gacc[tid] = 0.f;
    // ---- gather phase: 128 nodes x 2 lanes ----
    {
        const int g = tid >> 1, l = tid & 1;
        const int n = blockIdx.x * 128 + g;
        if (n < N) {
            float acc[16];
#pragma unroll
            for (int j = 0; j < 16; ++j) acc[j] = 0.f;
            gather_row16(row_start, esrc, IN, n, l, acc);
            const float dv = dinv[n];
#pragma unroll
            for (int j = 0; j < 16; ++j) Yb[g][l * 16 + j] = (half_t)(dv * acc[j]);
        } else {
#pragma unroll
            for (int j = 0; j < 16; ++j) Yb[g][l * 16 + j] = (half_t)0.f;
        }
    }
    __syncthreads();
    // ---- tail phase: wave wid handles 32 nodes as two 16-node tiles ----
    const int wid = tid >> 6, lane = tid & 63;
    const int quad = lane >> 4, n16 = lane & 15;
    const int nnv = nn_p[0];
    const float bm2v = bm2[0];
#pragma unroll
    for (int t2 = 0; t2 < 2; ++t2) {
        const int n0 = blockIdx.x * 128 + wid * 32 + t2 * 16;
        if (n0 >= N) break;
        half8 a1 = *(const half8*)&Yb[wid * 32 + t2 * 16 + n16][quad * 8];
        f32x4 acc1[4];
#pragma unroll
        for (int t = 0; t < 4; ++t) {
            half8 bf = *(const half8*)(W2t + (size_t)(t * 16 + n16) * 32 + quad * 8);
            f32x4 z = {0.f, 0.f, 0.f, 0.f};
            acc1[t] = __builtin_amdgcn_mfma_f32_16x16x32_f16(a1, bf, z, 0, 0, 0);
        }
#pragma unroll
        for (int t = 0; t < 4; ++t) {
            int c = t * 16 + n16;
            float bb = b2[c];
#pragma unroll
            for (int r = 0; r < 4; ++r)
                Hb[wid][quad * 4 + r][c] = (half_t)fmaxf(acc1[t][r] + bb, 0.f);
        }
        half8 a2lo = *(const half8*)&Hb[wid][n16][quad * 8];
        half8 a2hi = *(const half8*)&Hb[wid][n16][32 + quad * 8];
        f32x4 acc2[4];
#pragma unroll
        for (int t = 0; t < 4; ++t) {
            half8 b0 = *(const half8*)(Wm1t + (size_t)(t * 16 + n16) * 64 + quad * 8);
            half8 b1 = *(const half8*)(Wm1t + (size_t)(t * 16 + n16) * 64 + 32 + quad * 8);
            f32x4 a = {0.f, 0.f, 0.f, 0.f};
            a = __builtin_amdgcn_mfma_f32_16x16x32_f16(a2lo, b0, a, 0, 0, 0);
            a = __builtin_amdgcn_mfma_f32_16x16x32_f16(a2hi, b1, a, 0, 0, 0);
            acc2[t] = a;
        }
        float vsum[4] = {0.f, 0.f, 0.f, 0.f};
#pragma unroll
        for (int t = 0; t < 4; ++t) {
            int c = t * 16 + n16;
            float bb = bm1[c], ww = Wm2[c];
#pragma unroll
            for (int r = 0; r < 4; ++r)
                vsum[r] += fmaxf(acc2[t][r] + bb, 0.f) * ww;
        }
#pragma unroll
        for (int m = 1; m < 16; m <<= 1) {
#pragma unroll
            for (int r = 0; r < 4; ++r) vsum[r] += __shfl_xor(vsum[r], m, 64);
        }
        if (n16 == 0) {
#pragma unroll
            for (int r = 0; r < 4; ++r) {
                int n = n0 + quad * 4 + r;
                if (n < N) {
                    int g = n / nnv;
                    if (g < 32) atomicAdd(&gacc[g], vsum[r] + bm2v);
                }
            }
        }
    }
    __syncthreads();
    if (tid < n_graphs && tid < 32) atomicAdd(&out[tid], gacc[tid] / (float)nnv);
}

// ---- fallback (atomic) path ----------------------------------------------
__global__ void k_zero_int(int* p, int n) {
    int i = blockIdx.x * blockDim.x + threadIdx.x;
    if (i < n) p[i] = 0;
}
__global__ void k_hist(const int* __restrict__ dst, int* __restrict__ deg, int E) {
    int e = blockIdx.x * blockDim.x + threadIdx.x;
    if (e < E) atomicAdd(&deg[dst[e]], 1);
}
__global__ void k_dinv(const int* __restrict__ deg, float* __restrict__ dinv, int n) {
    int i = blockIdx.x * blockDim.x + threadIdx.x;
    if (i < n) dinv[i] = rsqrtf(1.0f + (float)deg[i]);
}
__global__ __launch_bounds__(256) void k_gemm1f(
    const float* __restrict__ x, const float* __restrict__ W,
    const float* __restrict__ dinv, float* __restrict__ hs1, int N)
{
    __shared__ float Wl[128 * 32];
    __shared__ __align__(16) float Xl[8 * 132];
    const int tid = threadIdx.x;
    for (int i = tid; i < 128 * 32; i += 256) Wl[i] = W[i];
    const int node0 = blockIdx.x * 8;
    {
        int r = tid >> 5, c4 = tid & 31;
        int node = node0 + r;
        float4 v = make_float4(0.f, 0.f, 0.f, 0.f);
        if (node < N) v = ((const float4*)(x + (size_t)node * 128))[c4];
        *(float4*)&Xl[r * 132 + c4 * 4] = v;
    }
    __syncthreads();
    const int row = tid >> 5, f = tid & 31;
    float acc = 0.f;
#pragma unroll
    for (int k = 0; k < 128; k += 4) {
        float4 xv = *(const float4*)&Xl[row * 132 + k];
        acc += xv.x * Wl[(k + 0) * 32 + f];
        acc += xv.y * Wl[(k + 1) * 32 + f];
        acc += xv.z * Wl[(k + 2) * 32 + f];
        acc += xv.w * Wl[(k + 3) * 32 + f];
    }
    const int node = node0 + row;
    if (node < N) hs1[(size_t)node * 32 + f] = acc * dinv[node];
}
__global__ __launch_bounds__(256) void k_gemm2(
    const float* __restrict__ agg1, const float* __restrict__ W,
    const float* __restrict__ dinv, float* __restrict__ hs2, int N)
{
    __shared__ float Wl[32 * 64];
    __shared__ __align__(16) float Zl[4 * 36];
    const int tid = threadIdx.x;
    for (int i = tid; i < 32 * 64; i += 256) Wl[i] = W[i];
    const int node0 = blockIdx.x * 4;
    if (tid < 128) {
        int r = tid >> 5, c = tid & 31;
        int node = node0 + r;
        float v = 0.f;
        if (node < N) v = fmaxf(agg1[(size_t)node * 32 + c], 0.f);
        Zl[r * 36 + c] = v;
    }
    __syncthreads();
    const int row = tid >> 6, f = tid & 63;
    float acc = 0.f;
#pragma unroll
    for (int k = 0; k < 32; k += 4) {
        float4 zv = *(const float4*)&Zl[row * 36 + k];
        acc += zv.x * Wl[(k + 0) * 64 + f];
        acc += zv.y * Wl[(k + 1) * 64 + f];
        acc += zv.z * Wl[(k + 2) * 64 + f];
        acc += zv.w * Wl[(k + 3) * 64 + f];
    }
    int node = node0 + row;
    if (node < N) hs2[(size_t)node * 64 + f] = acc * dinv[node];
}
template <int F>
__global__ void k_agg_init(const float* __restrict__ hs, const float* __restrict__ b,
                           const float* __restrict__ dinv, float* __restrict__ agg, int N)
{
    long long t = (long long)blockIdx.x * blockDim.x + threadIdx.x;
    int n = (int)(t / F), f = (int)(t % F);
    if (n < N) agg[(size_t)n * F + f] = hs[(size_t)n * F + f] * dinv[n] + b[f];
}
template <int F>
__global__ void k_edge_atomic(const int* __restrict__ ei, const float* __restrict__ hs,
                              const float* __restrict__ dinv, float* __restrict__ agg, int E)
{
    long long tid = (long long)blockIdx.x * blockDim.x + threadIdx.x;
    int e = (int)(tid / F), f = (int)(tid % F);
    if (e < E) {
        int s = ei[e], d = ei[E + e];
        atomicAdd(&agg[(size_t)d * F + f], hs[(size_t)s * F + f] * dinv[d]);
    }
}
__global__ __launch_bounds__(256) void k_mlp(
    const float* __restrict__ agg2, const float* __restrict__ Wm1,
    const float* __restrict__ bm1, const float* __restrict__ Wm2,
    const float* __restrict__ bm2, float* __restrict__ vout, int N)
{
    __shared__ float Wl[64 * 64];
    __shared__ float W2l[64];
    __shared__ __align__(16) float Zl[4][64];
    const int tid = threadIdx.x;
    for (int i = tid; i < 64 * 64; i += 256) Wl[i] = Wm1[i];
    if (tid < 64) W2l[tid] = Wm2[tid];
    const int wid = tid >> 6, lane = tid & 63;
    const int node = blockIdx.x * 4 + wid;
    float zv = 0.f;
    if (node < N) zv = fmaxf(agg2[(size_t)node * 64 + lane], 0.f);
    Zl[wid][lane] = zv;
    __syncthreads();
    float t = bm1[lane];
#pragma unroll
    for (int k = 0; k < 64; k += 4) {
        float4 z4 = *(const float4*)&Zl[wid][k];
        t += z4.x * Wl[(k + 0) * 64 + lane];
        t += z4.y * Wl[(k + 1) * 64 + lane];
        t += z4.z * Wl[(k + 2) * 64 + lane];
        t += z4.w * Wl[(k + 3) * 64 + lane];
    }
    t = fmaxf(t, 0.f);
    float val = t * W2l[lane];
#pragma unroll
    for (int off = 32; off > 0; off >>= 1) val += __shfl_down(val, off, 64);
    if (lane == 0 && node < N) vout[node] = val + bm2[0];
}
__global__ void k_reduce(const float* __restrict__ v, const int* __restrict__ num_nodes_p,
                         float* out, int N, int n_graphs)
{
    __shared__ float acc[32];
    int tid = threadIdx.x;
    if (tid < n_graphs) acc[tid] = 0.f;
    __syncthreads();
    int i = blockIdx.x * blockDim.x + tid;
    int nn = num_nodes_p[0];
    if (i < N) {
        int g = i / nn;
        if (g < n_graphs) atomicAdd(&acc[g], v[i]);
    }
    __syncthreads();
    if (tid < n_graphs) atomicAdd(&out[tid], acc[tid] / (float)nn);
}
// ---------------------------------------------------------------------------

extern "C" void kernel_launch(void* const* d_in, const int* in_sizes, int n_in,
                              void* d_out, int out_size, void* d_ws, size_t ws_size,
                              hipStream_t stream)
{
    const float* x   = (const float*)d_in[0];
    const float* W1  = (const float*)d_in[1];
    const float* b1  = (const float*)d_in[2];
    const float* W2  = (const float*)d_in[3];
    const float* b2  = (const float*)d_in[4];
    const float* Wm1 = (const float*)d_in[5];
    const float* bm1 = (const float*)d_in[6];
    const float* Wm2 = (const float*)d_in[7];
    const float* bm2 = (const float*)d_in[8];
    const int*   ei  = (const int*)d_in[9];
    const int*   nn  = (const int*)d_in[10];
    const int N = in_sizes[0] / 128;
    const int E = in_sizes[9] / 2;
    float* out = (float*)d_out;

    const int NB = (N + BKN - 1) / BKN;
    const int nblk = (E + CHUNK - 1) / CHUNK;
    const long long T = (long long)NB * nblk;
    const int nb1 = (int)((T + 255) / 256);
    auto al4 = [](size_t v) { return (v + 3) & ~(size_t)3; };
    const size_t need_ints = al4(T) + al4(T + 1) + 1024 + al4(E) + al4(E)
                           + al4(N + 1) + al4(N) + 8ull * N + 8ull * N
                           + 5120 + 64;
    const bool use_new = (N <= 131072) && (T <= 262144) && (nb1 <= 1024)
                       && (NB <= NBMAX) && (out_size <= 32)
                       && (ws_size >= need_ints * sizeof(int));

    if (use_new) {
        int* w = (int*)d_ws;
        int*    table     = w;                          w += al4(T);
        int*    S         = w;                          w += al4(T + 1);
        int*    bsums     = w;                          w += 1024;
        int*    codes     = w;                          w += al4(E);
        int*    esrc      = w;                          w += al4(E);
        int*    row_start = w;                          w += al4(N + 1);
        float*  dinv      = (float*)w;                  w += al4(N);
        int*    hs8       = w;                          w += 8ull * N;   // fp8 rows, 32 B
        int*    Zs8       = w;                          w += 8ull * N;   // fp8 rows
        half_t* W1t       = (half_t*)w;                 // 4096 halves
        half_t* W2t       = W1t + 4096;                 // 2048 halves
        half_t* Wm1t      = W2t + 2048;                 // 4096 halves

        k_count_coarse<<<nblk, 256, 0, stream>>>(ei + E, table, E, nblk, NB);
        k_scan1<<<nb1, 256, 0, stream>>>(table, S, bsums, (int)T);
        k_scan2<<<1, 1024, 0, stream>>>(bsums, nb1);
        k_scatter2<<<nblk, 256, 0, stream>>>(ei, S, bsums, codes, E, nblk, NB);
        k_fine<<<NB, 512, 0, stream>>>(codes, S, bsums, esrc, row_start, dinv, nblk, N, E, NB);
        k_prep<<<16, 256, 0, stream>>>(W1, W2, Wm1, W1t, W2t, Wm1t, out, out_size);
        k_gemm1_mfma<<<(N + 63) / 64, 256, 0, stream>>>(x, W1t, dinv, (unsigned char*)hs8, N);
        k_agg8_l1<<<(N + 127) / 128, 256, 0, stream>>>(row_start, esrc, hs8, b1, dinv, Zs8, N);
        k_agg8_tail<<<(N + 127) / 128, 256, 0, stream>>>(row_start, esrc, Zs8, dinv,
                                                         W2t, b2, Wm1t, bm1, Wm2, bm2,
                                                         nn, out, N, out_size);
    } else {
        // fallback: fp32 atomic scatter path
        const size_t Ns = (size_t)N;
        float* dinv = (float*)d_ws;
        float* B    = dinv + N;
        float* hs1  = B;
        float* agg1 = B + 32 * Ns;
        float* hs2  = B + 64 * Ns;
        float* agg2 = B + 128 * Ns;
        float* vtmp = B;
        int*   deg  = (int*)B;

        const int nb = (N + 255) / 256;
        k_zero_out<<<1, 64, 0, stream>>>(out, out_size);
        k_zero_int<<<nb, 256, 0, stream>>>(deg, N);
        k_hist<<<(E + 255) / 256, 256, 0, stream>>>(ei + E, deg, E);
        k_dinv<<<nb, 256, 0, stream>>>(deg, dinv, N);
        k_gemm1f<<<(N + 7) / 8, 256, 0, stream>>>(x, W1, dinv, hs1, N);
        {
            long long t = (long long)N * 32;
            k_agg_init<32><<<(unsigned)((t + 255) / 256), 256, 0, stream>>>(hs1, b1, dinv, agg1, N);
            t = (long long)E * 32;
            k_edge_atomic<32><<<(unsigned)((t + 255) / 256), 256, 0, stream>>>(ei, hs1, dinv, agg1, E);
        }
        k_gemm2<<<(N + 3) / 4, 256, 0, stream>>>(agg1, W2, dinv, hs2, N);
        {
            long long t = (long long)N * 64;
            k_agg_init<64><<<(unsigned)((t + 255) / 256), 256, 0, stream>>>(hs2, b2, dinv, agg2, N);
            t = (long long)E * 64;
            k_edge_atomic<64><<<(unsigned)((t + 255) / 256), 256, 0, stream>>>(ei, hs2, dinv, agg2, E);
        }
        k_mlp<<<(N + 3) / 4, 256, 0, stream>>>(agg2, Wm1, bm1, Wm2, bm2, vtmp, N);
        k_reduce<<<nb, 256, 0, stream>>>(vtmp, nn, out, N, out_size);
    }
}